// Round 14
// baseline (247.883 us; speedup 1.0000x reference)
//
#include <hip/hip_runtime.h>
#include <hip/hip_bf16.h>

// ROUND 29 (resubmit -- container infra failure, no counters; kernel audited
// clean: uniform barriers, disjoint R/W buffers, bounds OK).
// r28 WIN (238.2). Arithmetic re-check: agg VALU work ~5us vs 38us
// measured, FETCH 81MB @ 2.1 TB/s -> agg is FETCH-bound (random gather, 40%
// L2 miss, structural). Stop shaving VALU; cut round-trips instead.
// Change: fuse agg1+gemm2. 1563 blocks; 4 waves x 8 nodes agg -> LDS hb tile
// (132-stride pad) -> syncthreads -> LDS-A gemm2. hb never hits global
// (-6.4MB wr, -6.4MB rd, -1 gap). Layer-2 outputs go to qb2/kvb2/sb2 to
// avoid racing the layer-1 kvb gather. Tail nodes write zero rows.
// Predict: 238.2 -> ~228-232. If regression: fusion hurt latency hiding ->
// revert to split dispatches.

#define N_NODES 50000
#define N_EDGES 800000
#define NPAD    50048
#define GEMM_BLKS 1563 // ceil(50000/32), 32-row tiles
#define EPB 2048       // edges per scatter block
#define SCAT_BLKS 391  // ceil(800000/2048)
#define NBK 196        // buckets of 256 nodes (dst>>8)
#define CAP 6144       // fixed pairs window per bucket
#define CAPT 24        // CAP/256 per-thread reg hold in passB
#define CURSTRIDE 16   // one cursor per 64B line
#define ALDS 132       // padded LDS row stride (bf16 units)

using bf16 = __hip_bfloat16;
typedef __attribute__((ext_vector_type(8))) short bf16x8;
typedef __attribute__((ext_vector_type(4))) short bf16x4;
typedef __attribute__((ext_vector_type(4))) float f32x4;
typedef __attribute__((ext_vector_type(4))) unsigned int u32x4;
typedef __attribute__((ext_vector_type(2))) unsigned int u32x2;

__device__ __forceinline__ float b2f(unsigned short u) {
    unsigned int x = ((unsigned int)u) << 16;
    return __builtin_bit_cast(float, x);
}
__device__ __forceinline__ float lo_f(unsigned int u) {
    return __builtin_bit_cast(float, u << 16);
}
__device__ __forceinline__ float hi_f(unsigned int u) {
    return __builtin_bit_cast(float, u & 0xffff0000u);
}
__device__ __forceinline__ short f2b(float f) {
    return (short)__builtin_bit_cast(unsigned short, __float2bfloat16(f));
}

// DPP add helpers (verified on HW r24/r25).
template <int CTRL>
__device__ __forceinline__ float dadd(float p) {
    int vi = __builtin_bit_cast(int, p);
    int mv = __builtin_amdgcn_update_dpp(vi, vi, CTRL, 0xF, 0xF, false);
    return p + __builtin_bit_cast(float, mv);
}
template <int H>
__device__ __forceinline__ float edge_reduce(float p) {
    p = dadd<0xB1>(p);
    p = dadd<0x4E>(p);
    if constexpr (H == 1) {
        p = dadd<0x124>(p);  // row_ror:4
        p = dadd<0x128>(p);  // row_ror:8
    }
    return p;
}

struct WPtrs { const float* p[8]; };

// ---- per-node aggregation core (4 edge-slots/wave, 16 lanes/slot, 4
// dims/lane). Computes v0..v3 for lane<16 (softmax agg + skip + optional
// relu). Caller stores. ----
template <int H, bool RELU>
__device__ __forceinline__ void agg_node(
    int n, int lane, int slot, int m,
    const int* __restrict__ off, const unsigned short* __restrict__ csr_src,
    const bf16* __restrict__ qb, const unsigned int* __restrict__ kvu,
    const bf16* __restrict__ sb,
    float& v0, float& v1, float& v2, float& v3) {
    const float SC = ((H == 4) ? 0.25f : 0.125f) * 1.4426950408889634f;

    const unsigned int* qp = (const unsigned int*)qb + (size_t)n * 32 + m * 2;
    const unsigned int q01 = qp[0], q23 = qp[1];
    const float qf0 = lo_f(q01), qf1 = hi_f(q01);
    const float qf2 = lo_f(q23), qf3 = hi_f(q23);

    float a0 = 0.f, a1 = 0.f, a2 = 0.f, a3 = 0.f, ds = 0.f;
    int jb = off[n];
    const int j1 = off[n + 1];
    const unsigned int mb = (unsigned)m * 4;

    for (; jb + 8 <= j1; jb += 8) {
        const unsigned s0 = (unsigned)csr_src[jb + slot];
        const unsigned s1 = (unsigned)csr_src[jb + 4 + slot];
        u32x4 w0 = *(const u32x4*)(kvu + (((size_t)s0) << 6) + mb);
        u32x4 w1 = *(const u32x4*)(kvu + (((size_t)s1) << 6) + mb);
        float p0 = qf0 * lo_f(w0[0]);
        p0 = fmaf(qf1, lo_f(w0[1]), p0);
        p0 = fmaf(qf2, lo_f(w0[2]), p0);
        p0 = fmaf(qf3, lo_f(w0[3]), p0);
        float p1 = qf0 * lo_f(w1[0]);
        p1 = fmaf(qf1, lo_f(w1[1]), p1);
        p1 = fmaf(qf2, lo_f(w1[2]), p1);
        p1 = fmaf(qf3, lo_f(w1[3]), p1);
        p0 = edge_reduce<H>(p0);
        p1 = edge_reduce<H>(p1);
        const float e0 = exp2f(p0 * SC);
        const float e1 = exp2f(p1 * SC);
        a0 = fmaf(e0, hi_f(w0[0]), a0); a0 = fmaf(e1, hi_f(w1[0]), a0);
        a1 = fmaf(e0, hi_f(w0[1]), a1); a1 = fmaf(e1, hi_f(w1[1]), a1);
        a2 = fmaf(e0, hi_f(w0[2]), a2); a2 = fmaf(e1, hi_f(w1[2]), a2);
        a3 = fmaf(e0, hi_f(w0[3]), a3); a3 = fmaf(e1, hi_f(w1[3]), a3);
        ds += e0 + e1;
    }
    for (; jb < j1; jb += 4) {
        int jc = jb + slot;
        const bool valid = jc < j1;
        if (!valid) jc = j1 - 1;
        const unsigned s0 = (unsigned)csr_src[jc];
        u32x4 w0 = *(const u32x4*)(kvu + (((size_t)s0) << 6) + mb);
        float p0 = qf0 * lo_f(w0[0]);
        p0 = fmaf(qf1, lo_f(w0[1]), p0);
        p0 = fmaf(qf2, lo_f(w0[2]), p0);
        p0 = fmaf(qf3, lo_f(w0[3]), p0);
        p0 = edge_reduce<H>(p0);
        const float e0 = valid ? exp2f(p0 * SC) : 0.f;
        a0 = fmaf(e0, hi_f(w0[0]), a0);
        a1 = fmaf(e0, hi_f(w0[1]), a1);
        a2 = fmaf(e0, hi_f(w0[2]), a2);
        a3 = fmaf(e0, hi_f(w0[3]), a3);
        ds += e0;
    }

    a0 += __shfl_xor(a0, 16, 64); a0 += __shfl_xor(a0, 32, 64);
    a1 += __shfl_xor(a1, 16, 64); a1 += __shfl_xor(a1, 32, 64);
    a2 += __shfl_xor(a2, 16, 64); a2 += __shfl_xor(a2, 32, 64);
    a3 += __shfl_xor(a3, 16, 64); a3 += __shfl_xor(a3, 32, 64);
    ds += __shfl_xor(ds, 16, 64); ds += __shfl_xor(ds, 32, 64);

    if (lane < 16) {
        const float inv = (ds != 0.f) ? 1.f / ds : 0.f;
        const unsigned int* sp = (const unsigned int*)sb + (size_t)n * 32 + m * 2;
        const unsigned int s01 = sp[0], s23 = sp[1];
        v0 = fmaf(a0, inv, lo_f(s01));
        v1 = fmaf(a1, inv, hi_f(s01));
        v2 = fmaf(a2, inv, lo_f(s23));
        v3 = fmaf(a3, inv, hi_f(s23));
        if (RELU) {
            v0 = fmaxf(v0, 0.f); v1 = fmaxf(v1, 0.f);
            v2 = fmaxf(v2, 0.f); v3 = fmaxf(v3, 0.f);
        }
    }
}

// ---------------- prep: conv_w + gcur zero (tiny) ----------------
__global__ __launch_bounds__(256) void prep(WPtrs wp, bf16* __restrict__ wb,
                                            int* __restrict__ gcur) {
    const int gs = gridDim.x * 256;
    const int t0 = blockIdx.x * 256 + threadIdx.x;
    if (t0 < NBK * CURSTRIDE) gcur[t0] = 0;
    for (int i = t0; i < 49152; i += gs) {
        int y, o;
        if (i < 32768) { y = i >> 13; o = i & 8191; }
        else { y = 4 + ((i - 32768) >> 12); o = (i - 32768) & 4095; }
        wb[i] = __float2bfloat16(wp.p[y][o]);
    }
}

// ------------- MFMA GEMM body (32-row tile, 4 weight mats) -------------
template <int K, bool LDSA>
__device__ __forceinline__ void gemm_body(
    int blk, int tid,
    const bf16* __restrict__ A, const bf16* __restrict__ wb,
    const float* __restrict__ bq, const float* __restrict__ bk,
    const float* __restrict__ bv, const float* __restrict__ bs,
    bf16* __restrict__ qb, bf16* __restrict__ kvb, bf16* __restrict__ sb) {
    const int wave = tid >> 6;
    const int lane = tid & 63;
    const int row0 = blk * 32;
    const int m  = lane & 15;
    const int kg = lane >> 4;
    const bf16* W = wb + (size_t)wave * 64 * K;

    f32x4 acc[2][4];
#pragma unroll
    for (int i = 0; i < 2; ++i)
#pragma unroll
        for (int j = 0; j < 4; ++j) acc[i][j] = (f32x4){0.f, 0.f, 0.f, 0.f};

#pragma unroll
    for (int k0 = 0; k0 < K; k0 += 32) {
        bf16x8 a[2], b[4];
#pragma unroll
        for (int i = 0; i < 2; ++i) {
            if constexpr (LDSA) {
                const bf16* ap = A + (size_t)(i * 16 + m) * ALDS + k0 + kg * 8;
                bf16x4 lo = *(const bf16x4*)ap;
                bf16x4 hi = *(const bf16x4*)(ap + 4);
#pragma unroll
                for (int q = 0; q < 4; ++q) { a[i][q] = lo[q]; a[i][q + 4] = hi[q]; }
            } else {
                a[i] = *(const bf16x8*)(A + (size_t)(row0 + i * 16 + m) * K + k0 + kg * 8);
            }
        }
#pragma unroll
        for (int j = 0; j < 4; ++j)
            b[j] = *(const bf16x8*)(W + (size_t)(j * 16 + m) * K + k0 + kg * 8);
#pragma unroll
        for (int i = 0; i < 2; ++i)
#pragma unroll
            for (int j = 0; j < 4; ++j)
                acc[i][j] = __builtin_amdgcn_mfma_f32_16x16x32_bf16(a[i], b[j], acc[i][j], 0, 0, 0);
    }

    const int crow = (lane >> 4) * 4;
    const int ccol = lane & 15;
    const float* B = (wave == 0) ? bq : (wave == 1) ? bk : (wave == 2) ? bv : bs;
    float bias[4];
#pragma unroll
    for (int j = 0; j < 4; ++j) bias[j] = B[j * 16 + ccol];

#pragma unroll
    for (int i = 0; i < 2; ++i)
#pragma unroll
        for (int r = 0; r < 4; ++r) {
            int gr = row0 + i * 16 + crow + r;
            if (gr >= N_NODES) continue;
#pragma unroll
            for (int j = 0; j < 4; ++j) {
                float val = acc[i][j][r] + bias[j];
                size_t idx = (size_t)gr * 64 + j * 16 + ccol;
                if (wave == 0) qb[idx] = __float2bfloat16(val);
                else if (wave == 1) kvb[idx * 2] = __float2bfloat16(val);
                else if (wave == 2) kvb[idx * 2 + 1] = __float2bfloat16(val);
                else sb[idx] = __float2bfloat16(val);
            }
        }
}

// layer-1: scatter blocks first, then gemm blocks (f32 x staged via LDS).
__global__ __launch_bounds__(256) void gemm1_scatter(
    const float* __restrict__ x, const bf16* __restrict__ wb,
    const float* __restrict__ bq, const float* __restrict__ bk,
    const float* __restrict__ bv, const float* __restrict__ bs,
    bf16* __restrict__ qb, bf16* __restrict__ kvb, bf16* __restrict__ sb,
    const int* __restrict__ ei,
    int* __restrict__ gcur, unsigned int* __restrict__ pairs) {
    __shared__ union {
        struct {
            int hist[256];
            int sm[256];
            int obs[NBK];
            unsigned int stage[EPB];
        } s;
        bf16 As[32 * ALDS];
    } u;

    const int t = threadIdx.x;

    if (blockIdx.x >= SCAT_BLKS) {
        const int blk = blockIdx.x - SCAT_BLKS;
        const int row0 = blk * 32;
        {
            const int r = t >> 3;
            const int c0 = (t & 7) << 4;
            int gr = row0 + r;
            if (gr >= N_NODES) gr = N_NODES - 1;
            const float* px = x + (size_t)gr * 128 + c0;
            f32x4 v0 = *(const f32x4*)px;
            f32x4 v1 = *(const f32x4*)(px + 4);
            f32x4 v2 = *(const f32x4*)(px + 8);
            f32x4 v3 = *(const f32x4*)(px + 12);
            bf16* dst = u.As + r * ALDS + c0;
            bf16x4 o0 = {f2b(v0[0]), f2b(v0[1]), f2b(v0[2]), f2b(v0[3])};
            bf16x4 o1 = {f2b(v1[0]), f2b(v1[1]), f2b(v1[2]), f2b(v1[3])};
            bf16x4 o2 = {f2b(v2[0]), f2b(v2[1]), f2b(v2[2]), f2b(v2[3])};
            bf16x4 o3 = {f2b(v3[0]), f2b(v3[1]), f2b(v3[2]), f2b(v3[3])};
            *(bf16x4*)(dst)      = o0;
            *(bf16x4*)(dst + 4)  = o1;
            *(bf16x4*)(dst + 8)  = o2;
            *(bf16x4*)(dst + 12) = o3;
        }
        __syncthreads();
        gemm_body<128, true>(blk, t, u.As, wb, bq, bk, bv, bs, qb, kvb, sb);
        return;
    }

    const int e0 = blockIdx.x * EPB;
    u.s.hist[t] = 0;
    __syncthreads();

    unsigned int pk[8];
    int bb[8], rr[8];
#pragma unroll
    for (int uu = 0; uu < 8; ++uu) {
        const int e = e0 + uu * 256 + t;
        if (e < N_EDGES) {
            int d  = ei[N_EDGES + e];
            int sv = ei[e];
            pk[uu] = ((unsigned int)d << 16) | (unsigned int)sv;
            bb[uu] = d >> 8;
            rr[uu] = atomicAdd(&u.s.hist[bb[uu]], 1);
        } else {
            bb[uu] = -1;
        }
    }
    __syncthreads();

    int hv = u.s.hist[t];
    u.s.sm[t] = hv;
    __syncthreads();
    for (int st = 1; st < 256; st <<= 1) {
        int tmp = (t >= st) ? u.s.sm[t - st] : 0;
        __syncthreads();
        u.s.sm[t] += tmp;
        __syncthreads();
    }
    const int total = u.s.sm[255];

    if (t < NBK && hv > 0) {
        int g = atomicAdd(&gcur[t * CURSTRIDE], hv);
        u.s.obs[t] = t * CAP + g - (u.s.sm[t] - hv);
    }
    __syncthreads();

#pragma unroll
    for (int uu = 0; uu < 8; ++uu)
        if (bb[uu] >= 0)
            u.s.stage[(u.s.sm[bb[uu]] - u.s.hist[bb[uu]]) + rr[uu]] = pk[uu];
    __syncthreads();

    for (int j = t; j < total; j += 256) {
        unsigned int pr = u.s.stage[j];
        int b = pr >> 24;
        int pos = u.s.obs[b] + j;
        if (pos - b * CAP < CAP)
            pairs[pos] = pr;
    }
}

// Pass B: one block per bucket; single window read into registers.
__global__ __launch_bounds__(256) void passB(const int* __restrict__ gcur,
                                             const unsigned int* __restrict__ pairs,
                                             unsigned short* __restrict__ csr,
                                             int* __restrict__ off) {
    __shared__ int bsm[256];
    __shared__ int cnt[256];
    __shared__ int pfx[256];
    __shared__ int place[256];
    const int b = blockIdx.x;
    const int t = threadIdx.x;
    const int n0 = b << 8;
    const int nb = ((n0 + 256 < N_NODES) ? 256 : N_NODES - n0);

    int gv = (t < NBK) ? gcur[t * CURSTRIDE] : 0;
    bsm[t] = (t < b) ? gv : 0;
    cnt[t] = 0;
    place[t] = 0;
    __syncthreads();
    for (int st = 128; st >= 1; st >>= 1) {
        if (t < st) bsm[t] += bsm[t + st];
        __syncthreads();
    }
    const int base = bsm[0];
    const int myCnt = gcur[b * CURSTRIDE];
    const unsigned int* win = pairs + (size_t)b * CAP;

    unsigned int pr[CAPT];
    int held = 0;
    for (int j = t; j < myCnt; j += 256) pr[held++] = win[j];

    for (int k = 0; k < held; ++k)
        atomicAdd(&cnt[(pr[k] >> 16) - n0], 1);
    __syncthreads();

    int cv = cnt[t];
    pfx[t] = cv;
    __syncthreads();
    for (int st = 1; st < 256; st <<= 1) {
        int tmp = (t >= st) ? pfx[t - st] : 0;
        __syncthreads();
        pfx[t] += tmp;
        __syncthreads();
    }
    const int excl = pfx[t] - cv;

    if (t < nb) off[n0 + t] = base + excl;
    if (b == NBK - 1 && t == 0) off[N_NODES] = base + myCnt;

    for (int k = 0; k < held; ++k) {
        unsigned int p = pr[k];
        int i = (int)(p >> 16) - n0;
        int r = atomicAdd(&place[i], 1);
        csr[base + (pfx[i] - cnt[i]) + r] = (unsigned short)(p & 0xffffu);
    }
}

// ---- FUSED layer-1 agg + layer-2 gemm: 4 waves x 8 nodes agg -> LDS hb
// tile -> syncthreads -> LDS-A gemm2 writing layer-2 buffers. ----
__global__ __launch_bounds__(256) void agg1_gemm2(
    const int* __restrict__ off, const unsigned short* __restrict__ csr_src,
    const bf16* __restrict__ qb, const unsigned int* __restrict__ kvu,
    const bf16* __restrict__ sb, const bf16* __restrict__ wb2,
    const float* __restrict__ bq2, const float* __restrict__ bk2,
    const float* __restrict__ bv2, const float* __restrict__ bs2,
    bf16* __restrict__ qb2, bf16* __restrict__ kvb2, bf16* __restrict__ sb2) {
    __shared__ bf16 As[32 * ALDS];
    const int t = threadIdx.x;
    const int wid = t >> 6;
    const int lane = t & 63;
    const int slot = lane >> 4;
    const int m = lane & 15;
    const int row0 = blockIdx.x * 32;

    // phase 1: aggregate 8 nodes per wave into the LDS tile
    for (int i = 0; i < 8; ++i) {
        const int r = wid * 8 + i;
        const int n = row0 + r;
        float v0 = 0.f, v1 = 0.f, v2 = 0.f, v3 = 0.f;
        if (n < N_NODES)
            agg_node<4, true>(n, lane, slot, m, off, csr_src, qb, kvu, sb,
                              v0, v1, v2, v3);
        if (lane < 16) {
            u32x2 o;
            o[0] = (unsigned)(unsigned short)f2b(v0) |
                   ((unsigned)(unsigned short)f2b(v1) << 16);
            o[1] = (unsigned)(unsigned short)f2b(v2) |
                   ((unsigned)(unsigned short)f2b(v3) << 16);
            *(u32x2*)((unsigned int*)As + r * (ALDS / 2) + m * 2) = o;
        }
    }
    __syncthreads();

    // phase 2: gemm2 on the LDS tile
    gemm_body<64, true>(blockIdx.x, t, As, wb2, bq2, bk2, bv2, bs2,
                        qb2, kvb2, sb2);
}

// ---- standalone aggregation (layer 2 -> d_out) ----
template <int H, bool RELU, typename OT>
__global__ __launch_bounds__(256) void agg_csr(const int* __restrict__ off,
                                               const unsigned short* __restrict__ csr_src,
                                               const bf16* __restrict__ qb,
                                               const unsigned int* __restrict__ kvu,
                                               const bf16* __restrict__ sb,
                                               OT* __restrict__ out) {
    const int lane = threadIdx.x & 63;
    const int slot = lane >> 4;
    const int m    = lane & 15;
    const int n = (blockIdx.x * 256 + threadIdx.x) >> 6;
    if (n >= N_NODES) return;

    float v0, v1, v2, v3;
    agg_node<H, RELU>(n, lane, slot, m, off, csr_src, qb, kvu, sb,
                      v0, v1, v2, v3);

    if (lane < 16) {
        if constexpr (__hip_internal::is_same<OT, bf16>::value) {
            u32x2 o;
            o[0] = (unsigned)(unsigned short)f2b(v0) |
                   ((unsigned)(unsigned short)f2b(v1) << 16);
            o[1] = (unsigned)(unsigned short)f2b(v2) |
                   ((unsigned)(unsigned short)f2b(v3) << 16);
            *(u32x2*)((unsigned int*)out + (size_t)n * 32 + m * 2) = o;
        } else {
            f32x4 o = (f32x4){v0, v1, v2, v3};
            __builtin_nontemporal_store(o, (f32x4*)((float*)out + (size_t)n * 64 + m * 4));
        }
    }
}

extern "C" void kernel_launch(void* const* d_in, const int* in_sizes, int n_in,
                              void* d_out, int out_size, void* d_ws, size_t ws_size,
                              hipStream_t stream) {
    const float* x  = (const float*)d_in[0];
    const int*   ei = (const int*)d_in[1];
    const float* bq1 = (const float*)d_in[3];
    const float* bk1 = (const float*)d_in[5];
    const float* bv1 = (const float*)d_in[7];
    const float* bs1 = (const float*)d_in[9];
    const float* bq2 = (const float*)d_in[11];
    const float* bk2 = (const float*)d_in[13];
    const float* bv2 = (const float*)d_in[15];
    const float* bs2 = (const float*)d_in[17];

    WPtrs wp;
    wp.p[0] = (const float*)d_in[2];
    wp.p[1] = (const float*)d_in[4];
    wp.p[2] = (const float*)d_in[6];
    wp.p[3] = (const float*)d_in[8];
    wp.p[4] = (const float*)d_in[10];
    wp.p[5] = (const float*)d_in[12];
    wp.p[6] = (const float*)d_in[14];
    wp.p[7] = (const float*)d_in[16];

    const size_t N = N_NODES;
    bf16* qb   = (bf16*)d_ws;                // N*64 (layer1 q)
    bf16* kvb  = qb + N * 64;                // 2*N*64 interleaved (layer1)
    bf16* wb   = kvb + 2 * N * 64;           // 49152
    bf16* sb   = wb + 49152;                 // N*64 (layer1 skip)
    bf16* qb2  = sb + N * 64;                // N*64 (layer2 q)
    bf16* kvb2 = qb2 + N * 64;               // 2*N*64 (layer2)
    bf16* sb2  = kvb2 + 2 * N * 64;          // N*64 (layer2 skip)
    int* off   = (int*)(sb2 + N * 64);       // N+1
    int* gcur  = off + N_NODES + 1;          // NBK*CURSTRIDE
    unsigned short* csr = (unsigned short*)(gcur + NBK * CURSTRIDE); // E u16
    unsigned int* pairs = (unsigned int*)(csr + N_EDGES);            // NBK*CAP

    const int aggGrid = (N_NODES * 64 + 255) / 256;

    // ---------------- prep (w-conv + gcur zero; tiny) ----------------
    prep<<<64, 256, 0, stream>>>(wp, wb, gcur);

    // ---------------- Layer 1 (scatter-first + gemm w/ LDS-staged x) -------
    gemm1_scatter<<<GEMM_BLKS + SCAT_BLKS, 256, 0, stream>>>(
        x, wb, bq1, bk1, bv1, bs1, qb, kvb, sb, ei, gcur, pairs);
    passB<<<NBK, 256, 0, stream>>>(gcur, pairs, csr, off);

    // ---------------- agg1 + gemm2 fused (hb stays in LDS) ----------------
    agg1_gemm2<<<GEMM_BLKS, 256, 0, stream>>>(
        off, csr, qb, (const unsigned int*)kvb, sb, wb + 32768,
        bq2, bk2, bv2, bs2, qb2, kvb2, sb2);

    // ---------------- Layer 2 aggregation -> output ----------------
    agg_csr<1, false, float><<<aggGrid, 256, 0, stream>>>(
        off, csr, qb2, (const unsigned int*)kvb2, sb2, (float*)d_out);
}

// Round 15
// 235.061 us; speedup vs baseline: 1.0545x; 1.0545x over previous
//
#include <hip/hip_runtime.h>
#include <hip/hip_bf16.h>

// ROUND 30. r29 FAILED (247.9, fused agg1_gemm2 = 70.7us vs 55 split; occ
// 32% vs 55%, VALU 30% vs 84%): fusion serialized 8 nodes/wave + barrier-
// coupled waves -> lost gather MLP worth ~15us to save ~2us of traffic.
// REVERT to r28 split structure (238.2 best). One new delta:
//   agg main loop 2 -> 4 gather batches in flight (16 edges/iter). In-flight
//   arithmetic says MLP (csr->kv dependency), not BW, limits the 2.1 TB/s
//   realized gather. +16 VGPR, occupancy knee not hit.
// Predict: agg 38 -> ~32-35 each, total -> ~228-234. If agg unchanged:
// 2.1 TB/s is a true gather floor -> structural.

#define N_NODES 50000
#define N_EDGES 800000
#define NPAD    50048
#define GEMM_BLKS 1563 // ceil(50000/32), 32-row tiles
#define EPB 2048       // edges per scatter block
#define SCAT_BLKS 391  // ceil(800000/2048)
#define NBK 196        // buckets of 256 nodes (dst>>8)
#define CAP 6144       // fixed pairs window per bucket
#define CAPT 24        // CAP/256 per-thread reg hold in passB
#define CURSTRIDE 16   // one cursor per 64B line
#define ALDS 132       // padded LDS row stride (bf16 units)

using bf16 = __hip_bfloat16;
typedef __attribute__((ext_vector_type(8))) short bf16x8;
typedef __attribute__((ext_vector_type(4))) short bf16x4;
typedef __attribute__((ext_vector_type(4))) float f32x4;
typedef __attribute__((ext_vector_type(4))) unsigned int u32x4;
typedef __attribute__((ext_vector_type(2))) unsigned int u32x2;

__device__ __forceinline__ float b2f(unsigned short u) {
    unsigned int x = ((unsigned int)u) << 16;
    return __builtin_bit_cast(float, x);
}
__device__ __forceinline__ float lo_f(unsigned int u) {
    return __builtin_bit_cast(float, u << 16);
}
__device__ __forceinline__ float hi_f(unsigned int u) {
    return __builtin_bit_cast(float, u & 0xffff0000u);
}
__device__ __forceinline__ short f2b(float f) {
    return (short)__builtin_bit_cast(unsigned short, __float2bfloat16(f));
}

// DPP add helpers (verified on HW r24/r25).
template <int CTRL>
__device__ __forceinline__ float dadd(float p) {
    int vi = __builtin_bit_cast(int, p);
    int mv = __builtin_amdgcn_update_dpp(vi, vi, CTRL, 0xF, 0xF, false);
    return p + __builtin_bit_cast(float, mv);
}
template <int H>
__device__ __forceinline__ float edge_reduce(float p) {
    p = dadd<0xB1>(p);
    p = dadd<0x4E>(p);
    if constexpr (H == 1) {
        p = dadd<0x124>(p);  // row_ror:4
        p = dadd<0x128>(p);  // row_ror:8
    }
    return p;
}

struct WPtrs { const float* p[8]; };

// ---------------- prep: conv_w + gcur zero (tiny) ----------------
__global__ __launch_bounds__(256) void prep(WPtrs wp, bf16* __restrict__ wb,
                                            int* __restrict__ gcur) {
    const int gs = gridDim.x * 256;
    const int t0 = blockIdx.x * 256 + threadIdx.x;
    if (t0 < NBK * CURSTRIDE) gcur[t0] = 0;
    for (int i = t0; i < 49152; i += gs) {
        int y, o;
        if (i < 32768) { y = i >> 13; o = i & 8191; }
        else { y = 4 + ((i - 32768) >> 12); o = (i - 32768) & 4095; }
        wb[i] = __float2bfloat16(wp.p[y][o]);
    }
}

// ------------- MFMA GEMM body (32-row tile, 4 weight mats) -------------
template <int K, bool LDSA>
__device__ __forceinline__ void gemm_body(
    int blk, int tid,
    const bf16* __restrict__ A, const bf16* __restrict__ wb,
    const float* __restrict__ bq, const float* __restrict__ bk,
    const float* __restrict__ bv, const float* __restrict__ bs,
    bf16* __restrict__ qb, bf16* __restrict__ kvb, bf16* __restrict__ sb) {
    const int wave = tid >> 6;
    const int lane = tid & 63;
    const int row0 = blk * 32;
    const int m  = lane & 15;
    const int kg = lane >> 4;
    const bf16* W = wb + (size_t)wave * 64 * K;

    f32x4 acc[2][4];
#pragma unroll
    for (int i = 0; i < 2; ++i)
#pragma unroll
        for (int j = 0; j < 4; ++j) acc[i][j] = (f32x4){0.f, 0.f, 0.f, 0.f};

#pragma unroll
    for (int k0 = 0; k0 < K; k0 += 32) {
        bf16x8 a[2], b[4];
#pragma unroll
        for (int i = 0; i < 2; ++i) {
            if constexpr (LDSA) {
                const bf16* ap = A + (size_t)(i * 16 + m) * ALDS + k0 + kg * 8;
                bf16x4 lo = *(const bf16x4*)ap;
                bf16x4 hi = *(const bf16x4*)(ap + 4);
#pragma unroll
                for (int q = 0; q < 4; ++q) { a[i][q] = lo[q]; a[i][q + 4] = hi[q]; }
            } else {
                a[i] = *(const bf16x8*)(A + (size_t)(row0 + i * 16 + m) * K + k0 + kg * 8);
            }
        }
#pragma unroll
        for (int j = 0; j < 4; ++j)
            b[j] = *(const bf16x8*)(W + (size_t)(j * 16 + m) * K + k0 + kg * 8);
#pragma unroll
        for (int i = 0; i < 2; ++i)
#pragma unroll
            for (int j = 0; j < 4; ++j)
                acc[i][j] = __builtin_amdgcn_mfma_f32_16x16x32_bf16(a[i], b[j], acc[i][j], 0, 0, 0);
    }

    const int crow = (lane >> 4) * 4;
    const int ccol = lane & 15;
    const float* B = (wave == 0) ? bq : (wave == 1) ? bk : (wave == 2) ? bv : bs;
    float bias[4];
#pragma unroll
    for (int j = 0; j < 4; ++j) bias[j] = B[j * 16 + ccol];

#pragma unroll
    for (int i = 0; i < 2; ++i)
#pragma unroll
        for (int r = 0; r < 4; ++r) {
            int gr = row0 + i * 16 + crow + r;
            if (gr >= N_NODES) continue;
#pragma unroll
            for (int j = 0; j < 4; ++j) {
                float val = acc[i][j][r] + bias[j];
                size_t idx = (size_t)gr * 64 + j * 16 + ccol;
                if (wave == 0) qb[idx] = __float2bfloat16(val);
                else if (wave == 1) kvb[idx * 2] = __float2bfloat16(val);
                else if (wave == 2) kvb[idx * 2 + 1] = __float2bfloat16(val);
                else sb[idx] = __float2bfloat16(val);
            }
        }
}

// layer-1: scatter blocks first, then gemm blocks (f32 x staged via LDS).
__global__ __launch_bounds__(256) void gemm1_scatter(
    const float* __restrict__ x, const bf16* __restrict__ wb,
    const float* __restrict__ bq, const float* __restrict__ bk,
    const float* __restrict__ bv, const float* __restrict__ bs,
    bf16* __restrict__ qb, bf16* __restrict__ kvb, bf16* __restrict__ sb,
    const int* __restrict__ ei,
    int* __restrict__ gcur, unsigned int* __restrict__ pairs) {
    __shared__ union {
        struct {
            int hist[256];
            int sm[256];
            int obs[NBK];
            unsigned int stage[EPB];
        } s;
        bf16 As[32 * ALDS];
    } u;

    const int t = threadIdx.x;

    if (blockIdx.x >= SCAT_BLKS) {
        const int blk = blockIdx.x - SCAT_BLKS;
        const int row0 = blk * 32;
        {
            const int r = t >> 3;
            const int c0 = (t & 7) << 4;
            int gr = row0 + r;
            if (gr >= N_NODES) gr = N_NODES - 1;
            const float* px = x + (size_t)gr * 128 + c0;
            f32x4 v0 = *(const f32x4*)px;
            f32x4 v1 = *(const f32x4*)(px + 4);
            f32x4 v2 = *(const f32x4*)(px + 8);
            f32x4 v3 = *(const f32x4*)(px + 12);
            bf16* dst = u.As + r * ALDS + c0;
            bf16x4 o0 = {f2b(v0[0]), f2b(v0[1]), f2b(v0[2]), f2b(v0[3])};
            bf16x4 o1 = {f2b(v1[0]), f2b(v1[1]), f2b(v1[2]), f2b(v1[3])};
            bf16x4 o2 = {f2b(v2[0]), f2b(v2[1]), f2b(v2[2]), f2b(v2[3])};
            bf16x4 o3 = {f2b(v3[0]), f2b(v3[1]), f2b(v3[2]), f2b(v3[3])};
            *(bf16x4*)(dst)      = o0;
            *(bf16x4*)(dst + 4)  = o1;
            *(bf16x4*)(dst + 8)  = o2;
            *(bf16x4*)(dst + 12) = o3;
        }
        __syncthreads();
        gemm_body<128, true>(blk, t, u.As, wb, bq, bk, bv, bs, qb, kvb, sb);
        return;
    }

    const int e0 = blockIdx.x * EPB;
    u.s.hist[t] = 0;
    __syncthreads();

    unsigned int pk[8];
    int bb[8], rr[8];
#pragma unroll
    for (int uu = 0; uu < 8; ++uu) {
        const int e = e0 + uu * 256 + t;
        if (e < N_EDGES) {
            int d  = ei[N_EDGES + e];
            int sv = ei[e];
            pk[uu] = ((unsigned int)d << 16) | (unsigned int)sv;
            bb[uu] = d >> 8;
            rr[uu] = atomicAdd(&u.s.hist[bb[uu]], 1);
        } else {
            bb[uu] = -1;
        }
    }
    __syncthreads();

    int hv = u.s.hist[t];
    u.s.sm[t] = hv;
    __syncthreads();
    for (int st = 1; st < 256; st <<= 1) {
        int tmp = (t >= st) ? u.s.sm[t - st] : 0;
        __syncthreads();
        u.s.sm[t] += tmp;
        __syncthreads();
    }
    const int total = u.s.sm[255];

    if (t < NBK && hv > 0) {
        int g = atomicAdd(&gcur[t * CURSTRIDE], hv);
        u.s.obs[t] = t * CAP + g - (u.s.sm[t] - hv);
    }
    __syncthreads();

#pragma unroll
    for (int uu = 0; uu < 8; ++uu)
        if (bb[uu] >= 0)
            u.s.stage[(u.s.sm[bb[uu]] - u.s.hist[bb[uu]]) + rr[uu]] = pk[uu];
    __syncthreads();

    for (int j = t; j < total; j += 256) {
        unsigned int pr = u.s.stage[j];
        int b = pr >> 24;
        int pos = u.s.obs[b] + j;
        if (pos - b * CAP < CAP)
            pairs[pos] = pr;
    }
}

// Pass B: one block per bucket; single window read into registers.
__global__ __launch_bounds__(256) void passB(const int* __restrict__ gcur,
                                             const unsigned int* __restrict__ pairs,
                                             unsigned short* __restrict__ csr,
                                             int* __restrict__ off) {
    __shared__ int bsm[256];
    __shared__ int cnt[256];
    __shared__ int pfx[256];
    __shared__ int place[256];
    const int b = blockIdx.x;
    const int t = threadIdx.x;
    const int n0 = b << 8;
    const int nb = ((n0 + 256 < N_NODES) ? 256 : N_NODES - n0);

    int gv = (t < NBK) ? gcur[t * CURSTRIDE] : 0;
    bsm[t] = (t < b) ? gv : 0;
    cnt[t] = 0;
    place[t] = 0;
    __syncthreads();
    for (int st = 128; st >= 1; st >>= 1) {
        if (t < st) bsm[t] += bsm[t + st];
        __syncthreads();
    }
    const int base = bsm[0];
    const int myCnt = gcur[b * CURSTRIDE];
    const unsigned int* win = pairs + (size_t)b * CAP;

    unsigned int pr[CAPT];
    int held = 0;
    for (int j = t; j < myCnt; j += 256) pr[held++] = win[j];

    for (int k = 0; k < held; ++k)
        atomicAdd(&cnt[(pr[k] >> 16) - n0], 1);
    __syncthreads();

    int cv = cnt[t];
    pfx[t] = cv;
    __syncthreads();
    for (int st = 1; st < 256; st <<= 1) {
        int tmp = (t >= st) ? pfx[t - st] : 0;
        __syncthreads();
        pfx[t] += tmp;
        __syncthreads();
    }
    const int excl = pfx[t] - cv;

    if (t < nb) off[n0 + t] = base + excl;
    if (b == NBK - 1 && t == 0) off[N_NODES] = base + myCnt;

    for (int k = 0; k < held; ++k) {
        unsigned int p = pr[k];
        int i = (int)(p >> 16) - n0;
        int r = atomicAdd(&place[i], 1);
        csr[base + (pfx[i] - cnt[i]) + r] = (unsigned short)(p & 0xffffu);
    }
}

__global__ __launch_bounds__(256) void gemm2(
    const bf16* __restrict__ A, const bf16* __restrict__ wb,
    const float* __restrict__ bq, const float* __restrict__ bk,
    const float* __restrict__ bv, const float* __restrict__ bs,
    bf16* __restrict__ qb, bf16* __restrict__ kvb, bf16* __restrict__ sb) {
    gemm_body<64, false>(blockIdx.x, threadIdx.x, A, wb, bq, bk, bv, bs, qb, kvb, sb);
}

// ---- Aggregation: 4 edge-slots/wave, 16 lanes/slot, 4 dims/lane.
// Main loop: 4 gather batches (16 edges) in flight for MLP. ----
template <int H, bool RELU, typename OT>
__global__ __launch_bounds__(256) void agg_csr(const int* __restrict__ off,
                                               const unsigned short* __restrict__ csr_src,
                                               const bf16* __restrict__ qb,
                                               const unsigned int* __restrict__ kvu,
                                               const bf16* __restrict__ sb,
                                               OT* __restrict__ out) {
    const float SC = ((H == 4) ? 0.25f : 0.125f) * 1.4426950408889634f;
    const int lane = threadIdx.x & 63;
    const int slot = lane >> 4;
    const int m    = lane & 15;
    const int n = (blockIdx.x * 256 + threadIdx.x) >> 6;
    if (n >= N_NODES) return;

    const unsigned int* qp = (const unsigned int*)qb + (size_t)n * 32 + m * 2;
    const unsigned int q01 = qp[0], q23 = qp[1];
    const float qf0 = lo_f(q01), qf1 = hi_f(q01);
    const float qf2 = lo_f(q23), qf3 = hi_f(q23);

    float a0 = 0.f, a1 = 0.f, a2 = 0.f, a3 = 0.f, ds = 0.f;
    int jb = off[n];
    const int j1 = off[n + 1];
    const unsigned int mb = (unsigned)m * 4;

    // main: 4 batches (16 edges) in flight per iter
    for (; jb + 16 <= j1; jb += 16) {
        unsigned s[4];
#pragma unroll
        for (int bch = 0; bch < 4; ++bch)
            s[bch] = (unsigned)csr_src[jb + bch * 4 + slot];
        u32x4 w[4];
#pragma unroll
        for (int bch = 0; bch < 4; ++bch)
            w[bch] = *(const u32x4*)(kvu + (((size_t)s[bch]) << 6) + mb);
        float p[4];
#pragma unroll
        for (int bch = 0; bch < 4; ++bch) {
            float pp = qf0 * lo_f(w[bch][0]);
            pp = fmaf(qf1, lo_f(w[bch][1]), pp);
            pp = fmaf(qf2, lo_f(w[bch][2]), pp);
            pp = fmaf(qf3, lo_f(w[bch][3]), pp);
            p[bch] = pp;
        }
#pragma unroll
        for (int bch = 0; bch < 4; ++bch) p[bch] = edge_reduce<H>(p[bch]);
#pragma unroll
        for (int bch = 0; bch < 4; ++bch) {
            const float e = exp2f(p[bch] * SC);
            a0 = fmaf(e, hi_f(w[bch][0]), a0);
            a1 = fmaf(e, hi_f(w[bch][1]), a1);
            a2 = fmaf(e, hi_f(w[bch][2]), a2);
            a3 = fmaf(e, hi_f(w[bch][3]), a3);
            ds += e;
        }
    }
    // mid: 8-edge batches
    for (; jb + 8 <= j1; jb += 8) {
        const unsigned s0 = (unsigned)csr_src[jb + slot];
        const unsigned s1 = (unsigned)csr_src[jb + 4 + slot];
        u32x4 w0 = *(const u32x4*)(kvu + (((size_t)s0) << 6) + mb);
        u32x4 w1 = *(const u32x4*)(kvu + (((size_t)s1) << 6) + mb);
        float p0 = qf0 * lo_f(w0[0]);
        p0 = fmaf(qf1, lo_f(w0[1]), p0);
        p0 = fmaf(qf2, lo_f(w0[2]), p0);
        p0 = fmaf(qf3, lo_f(w0[3]), p0);
        float p1 = qf0 * lo_f(w1[0]);
        p1 = fmaf(qf1, lo_f(w1[1]), p1);
        p1 = fmaf(qf2, lo_f(w1[2]), p1);
        p1 = fmaf(qf3, lo_f(w1[3]), p1);
        p0 = edge_reduce<H>(p0);
        p1 = edge_reduce<H>(p1);
        const float e0 = exp2f(p0 * SC);
        const float e1 = exp2f(p1 * SC);
        a0 = fmaf(e0, hi_f(w0[0]), a0); a0 = fmaf(e1, hi_f(w1[0]), a0);
        a1 = fmaf(e0, hi_f(w0[1]), a1); a1 = fmaf(e1, hi_f(w1[1]), a1);
        a2 = fmaf(e0, hi_f(w0[2]), a2); a2 = fmaf(e1, hi_f(w1[2]), a2);
        a3 = fmaf(e0, hi_f(w0[3]), a3); a3 = fmaf(e1, hi_f(w1[3]), a3);
        ds += e0 + e1;
    }
    // tail: masked 4-edge batches
    for (; jb < j1; jb += 4) {
        int jc = jb + slot;
        const bool valid = jc < j1;
        if (!valid) jc = j1 - 1;
        const unsigned s0 = (unsigned)csr_src[jc];
        u32x4 w0 = *(const u32x4*)(kvu + (((size_t)s0) << 6) + mb);
        float p0 = qf0 * lo_f(w0[0]);
        p0 = fmaf(qf1, lo_f(w0[1]), p0);
        p0 = fmaf(qf2, lo_f(w0[2]), p0);
        p0 = fmaf(qf3, lo_f(w0[3]), p0);
        p0 = edge_reduce<H>(p0);
        const float e0 = valid ? exp2f(p0 * SC) : 0.f;
        a0 = fmaf(e0, hi_f(w0[0]), a0);
        a1 = fmaf(e0, hi_f(w0[1]), a1);
        a2 = fmaf(e0, hi_f(w0[2]), a2);
        a3 = fmaf(e0, hi_f(w0[3]), a3);
        ds += e0;
    }

    a0 += __shfl_xor(a0, 16, 64); a0 += __shfl_xor(a0, 32, 64);
    a1 += __shfl_xor(a1, 16, 64); a1 += __shfl_xor(a1, 32, 64);
    a2 += __shfl_xor(a2, 16, 64); a2 += __shfl_xor(a2, 32, 64);
    a3 += __shfl_xor(a3, 16, 64); a3 += __shfl_xor(a3, 32, 64);
    ds += __shfl_xor(ds, 16, 64); ds += __shfl_xor(ds, 32, 64);

    if (lane < 16) {
        const float inv = (ds != 0.f) ? 1.f / ds : 0.f;
        const unsigned int* sp = (const unsigned int*)sb + (size_t)n * 32 + m * 2;
        const unsigned int s01 = sp[0], s23 = sp[1];
        float v0 = fmaf(a0, inv, lo_f(s01));
        float v1 = fmaf(a1, inv, hi_f(s01));
        float v2 = fmaf(a2, inv, lo_f(s23));
        float v3 = fmaf(a3, inv, hi_f(s23));
        if (RELU) {
            v0 = fmaxf(v0, 0.f); v1 = fmaxf(v1, 0.f);
            v2 = fmaxf(v2, 0.f); v3 = fmaxf(v3, 0.f);
        }
        if constexpr (__hip_internal::is_same<OT, bf16>::value) {
            u32x2 o;
            o[0] = (unsigned)(unsigned short)f2b(v0) |
                   ((unsigned)(unsigned short)f2b(v1) << 16);
            o[1] = (unsigned)(unsigned short)f2b(v2) |
                   ((unsigned)(unsigned short)f2b(v3) << 16);
            *(u32x2*)((unsigned int*)out + (size_t)n * 32 + m * 2) = o;  // hb
        } else {
            f32x4 o = (f32x4){v0, v1, v2, v3};
            __builtin_nontemporal_store(o, (f32x4*)((float*)out + (size_t)n * 64 + m * 4));
        }
    }
}

extern "C" void kernel_launch(void* const* d_in, const int* in_sizes, int n_in,
                              void* d_out, int out_size, void* d_ws, size_t ws_size,
                              hipStream_t stream) {
    const float* x  = (const float*)d_in[0];
    const int*   ei = (const int*)d_in[1];
    const float* bq1 = (const float*)d_in[3];
    const float* bk1 = (const float*)d_in[5];
    const float* bv1 = (const float*)d_in[7];
    const float* bs1 = (const float*)d_in[9];
    const float* bq2 = (const float*)d_in[11];
    const float* bk2 = (const float*)d_in[13];
    const float* bv2 = (const float*)d_in[15];
    const float* bs2 = (const float*)d_in[17];

    WPtrs wp;
    wp.p[0] = (const float*)d_in[2];
    wp.p[1] = (const float*)d_in[4];
    wp.p[2] = (const float*)d_in[6];
    wp.p[3] = (const float*)d_in[8];
    wp.p[4] = (const float*)d_in[10];
    wp.p[5] = (const float*)d_in[12];
    wp.p[6] = (const float*)d_in[14];
    wp.p[7] = (const float*)d_in[16];

    const size_t N = N_NODES;
    bf16* hb  = (bf16*)d_ws;                 // NPAD*64
    bf16* qb  = hb + (size_t)NPAD * 64;      // N*64
    bf16* kvb = qb + N * 64;                 // 2*N*64 interleaved
    bf16* wb  = kvb + 2 * N * 64;            // 49152
    bf16* sb  = wb + 49152;                  // N*64 (bf16)
    int* off  = (int*)(sb + N * 64);         // N+1
    int* gcur = off + N_NODES + 1;           // NBK*CURSTRIDE
    unsigned short* csr = (unsigned short*)(gcur + NBK * CURSTRIDE); // E u16
    unsigned int* pairs = (unsigned int*)(csr + N_EDGES);            // NBK*CAP

    const int aggGrid = (N_NODES * 64 + 255) / 256;

    // ---------------- prep (w-conv + gcur zero; tiny) ----------------
    prep<<<64, 256, 0, stream>>>(wp, wb, gcur);

    // ---------------- Layer 1 (scatter-first + gemm w/ LDS-staged x) -------
    gemm1_scatter<<<GEMM_BLKS + SCAT_BLKS, 256, 0, stream>>>(
        x, wb, bq1, bk1, bv1, bs1, qb, kvb, sb, ei, gcur, pairs);
    passB<<<NBK, 256, 0, stream>>>(gcur, pairs, csr, off);
    agg_csr<4, true, bf16><<<aggGrid, 256, 0, stream>>>(off, csr, qb,
                                                        (const unsigned int*)kvb, sb, hb);

    // ---------------- Layer 2 ----------------
    gemm2<<<GEMM_BLKS, 256, 0, stream>>>(hb, wb + 32768, bq2, bk2, bv2, bs2,
                                         qb, kvb, sb);
    agg_csr<1, false, float><<<aggGrid, 256, 0, stream>>>(off, csr, qb,
                                                          (const unsigned int*)kvb, sb,
                                                          (float*)d_out);
}

// Round 16
// 222.173 us; speedup vs baseline: 1.1157x; 1.0580x over previous
//
#include <hip/hip_runtime.h>
#include <hip/hip_bf16.h>

// ROUND 31. r30 WIN (235.1). agg PROVEN at roofline: 204.8MB gather serviced
// in 36us = 5.7 TB/s combined L2+HBM (~90% of 6.3 achievable); 4 independent
// structures converged. Remaining slack: GEMM writeback = 32 scalar 2-B
// stores/thread = 12.8M VMEM store instrs/gemm ~ 20us issue-serialization
// (matches r22's all-idle signature: occ 26%, VALU 5%, HBM 12%).
// Change: LDS-transpose packed epilogue (2 passes: q+s then k+v in the 8.4KB
// tile) -> 4x16B coalesced stores/thread (8x fewer instrs). kv interleave
// built in LDS. Same rounding -> absmax unchanged.
// Predict: gemm1_scatter -12-18us, gemm2 -6-10us, total -> ~208-218.
// If <5us: store-issue theory wrong -> near-structural floor reached.

#define N_NODES 50000
#define N_EDGES 800000
#define NPAD    50048
#define GEMM_BLKS 1563 // ceil(50000/32), 32-row tiles
#define EPB 2048       // edges per scatter block
#define SCAT_BLKS 391  // ceil(800000/2048)
#define NBK 196        // buckets of 256 nodes (dst>>8)
#define CAP 6144       // fixed pairs window per bucket
#define CAPT 24        // CAP/256 per-thread reg hold in passB
#define CURSTRIDE 16   // one cursor per 64B line
#define ALDS 132       // padded LDS row stride (bf16 units), As = 32*132 = 4224
#define ELDS 66        // epilogue LDS row stride (bf16 units), 2 mats x 32*66 = 4224

using bf16 = __hip_bfloat16;
typedef __attribute__((ext_vector_type(8))) short bf16x8;
typedef __attribute__((ext_vector_type(4))) short bf16x4;
typedef __attribute__((ext_vector_type(4))) float f32x4;
typedef __attribute__((ext_vector_type(4))) unsigned int u32x4;
typedef __attribute__((ext_vector_type(2))) unsigned int u32x2;

__device__ __forceinline__ float b2f(unsigned short u) {
    unsigned int x = ((unsigned int)u) << 16;
    return __builtin_bit_cast(float, x);
}
__device__ __forceinline__ float lo_f(unsigned int u) {
    return __builtin_bit_cast(float, u << 16);
}
__device__ __forceinline__ float hi_f(unsigned int u) {
    return __builtin_bit_cast(float, u & 0xffff0000u);
}
__device__ __forceinline__ short f2b(float f) {
    return (short)__builtin_bit_cast(unsigned short, __float2bfloat16(f));
}

// DPP add helpers (verified on HW r24/r25).
template <int CTRL>
__device__ __forceinline__ float dadd(float p) {
    int vi = __builtin_bit_cast(int, p);
    int mv = __builtin_amdgcn_update_dpp(vi, vi, CTRL, 0xF, 0xF, false);
    return p + __builtin_bit_cast(float, mv);
}
template <int H>
__device__ __forceinline__ float edge_reduce(float p) {
    p = dadd<0xB1>(p);
    p = dadd<0x4E>(p);
    if constexpr (H == 1) {
        p = dadd<0x124>(p);  // row_ror:4
        p = dadd<0x128>(p);  // row_ror:8
    }
    return p;
}

struct WPtrs { const float* p[8]; };

// ---------------- prep: conv_w + gcur zero (tiny) ----------------
__global__ __launch_bounds__(256) void prep(WPtrs wp, bf16* __restrict__ wb,
                                            int* __restrict__ gcur) {
    const int gs = gridDim.x * 256;
    const int t0 = blockIdx.x * 256 + threadIdx.x;
    if (t0 < NBK * CURSTRIDE) gcur[t0] = 0;
    for (int i = t0; i < 49152; i += gs) {
        int y, o;
        if (i < 32768) { y = i >> 13; o = i & 8191; }
        else { y = 4 + ((i - 32768) >> 12); o = (i - 32768) & 4095; }
        wb[i] = __float2bfloat16(wp.p[y][o]);
    }
}

// ------------- MFMA GEMM body (32-row tile, 4 weight mats) -------------
// Ls: 4224-bf16 LDS scratch for the packed epilogue (may alias the A-tile
// for LDSA=true; epilogue syncs before overwriting).
template <int K, bool LDSA>
__device__ __forceinline__ void gemm_body(
    int blk, int tid, bf16* __restrict__ Ls,
    const bf16* __restrict__ A, const bf16* __restrict__ wb,
    const float* __restrict__ bq, const float* __restrict__ bk,
    const float* __restrict__ bv, const float* __restrict__ bs,
    bf16* __restrict__ qb, bf16* __restrict__ kvb, bf16* __restrict__ sb) {
    const int wave = tid >> 6;
    const int lane = tid & 63;
    const int row0 = blk * 32;
    const int m  = lane & 15;
    const int kg = lane >> 4;
    const bf16* W = wb + (size_t)wave * 64 * K;

    f32x4 acc[2][4];
#pragma unroll
    for (int i = 0; i < 2; ++i)
#pragma unroll
        for (int j = 0; j < 4; ++j) acc[i][j] = (f32x4){0.f, 0.f, 0.f, 0.f};

#pragma unroll
    for (int k0 = 0; k0 < K; k0 += 32) {
        bf16x8 a[2], b[4];
#pragma unroll
        for (int i = 0; i < 2; ++i) {
            if constexpr (LDSA) {
                const bf16* ap = A + (size_t)(i * 16 + m) * ALDS + k0 + kg * 8;
                bf16x4 lo = *(const bf16x4*)ap;
                bf16x4 hi = *(const bf16x4*)(ap + 4);
#pragma unroll
                for (int q = 0; q < 4; ++q) { a[i][q] = lo[q]; a[i][q + 4] = hi[q]; }
            } else {
                a[i] = *(const bf16x8*)(A + (size_t)(row0 + i * 16 + m) * K + k0 + kg * 8);
            }
        }
#pragma unroll
        for (int j = 0; j < 4; ++j)
            b[j] = *(const bf16x8*)(W + (size_t)(j * 16 + m) * K + k0 + kg * 8);
#pragma unroll
        for (int i = 0; i < 2; ++i)
#pragma unroll
            for (int j = 0; j < 4; ++j)
                acc[i][j] = __builtin_amdgcn_mfma_f32_16x16x32_bf16(a[i], b[j], acc[i][j], 0, 0, 0);
    }

    const int crow = (lane >> 4) * 4;
    const int ccol = lane & 15;
    const float* B = (wave == 0) ? bq : (wave == 1) ? bk : (wave == 2) ? bv : bs;
    float bias[4];
#pragma unroll
    for (int j = 0; j < 4; ++j) bias[j] = B[j * 16 + ccol];
#pragma unroll
    for (int i = 0; i < 2; ++i)
#pragma unroll
        for (int j = 0; j < 4; ++j)
#pragma unroll
            for (int r = 0; r < 4; ++r) acc[i][j][r] += bias[j];

    // ---- packed epilogue: LDS transpose -> 4x16B coalesced stores ----
    __syncthreads();  // k-loop LDS reads done (LDSA); waves aligned

    // pass A: q (wave0) -> Ls[0], s (wave3) -> Ls[2112]
    {
        bf16* dst = (wave == 0) ? Ls : (wave == 3) ? Ls + 32 * ELDS : nullptr;
        if (dst) {
#pragma unroll
            for (int i = 0; i < 2; ++i)
#pragma unroll
                for (int r = 0; r < 4; ++r) {
                    const int lr = i * 16 + crow + r;
#pragma unroll
                    for (int j = 0; j < 4; ++j)
                        dst[lr * ELDS + j * 16 + ccol] =
                            __float2bfloat16(acc[i][j][r]);
                }
        }
    }
    __syncthreads();
    {
        const int lr = tid >> 3;
        const int c0 = (tid & 7) << 3;
        const int gr = row0 + lr;
        if (gr < N_NODES) {
            const bf16* Lq = Ls + lr * ELDS + c0;
            const bf16* Lss = Ls + 32 * ELDS + lr * ELDS + c0;
            bf16x4 q0 = *(const bf16x4*)Lq;
            bf16x4 q1 = *(const bf16x4*)(Lq + 4);
            bf16x4 s0 = *(const bf16x4*)Lss;
            bf16x4 s1 = *(const bf16x4*)(Lss + 4);
            bf16x8 qv, sv;
#pragma unroll
            for (int q = 0; q < 4; ++q) {
                qv[q] = q0[q]; qv[q + 4] = q1[q];
                sv[q] = s0[q]; sv[q + 4] = s1[q];
            }
            *(bf16x8*)(qb + (size_t)gr * 64 + c0) = qv;
            *(bf16x8*)(sb + (size_t)gr * 64 + c0) = sv;
        }
    }
    __syncthreads();
    // pass B: k (wave1) -> Ls[0], v (wave2) -> Ls[2112]
    {
        bf16* dst = (wave == 1) ? Ls : (wave == 2) ? Ls + 32 * ELDS : nullptr;
        if (dst) {
#pragma unroll
            for (int i = 0; i < 2; ++i)
#pragma unroll
                for (int r = 0; r < 4; ++r) {
                    const int lr = i * 16 + crow + r;
#pragma unroll
                    for (int j = 0; j < 4; ++j)
                        dst[lr * ELDS + j * 16 + ccol] =
                            __float2bfloat16(acc[i][j][r]);
                }
        }
    }
    __syncthreads();
    {
        const int lr = tid >> 3;
        const int c0 = (tid & 7) << 3;  // 8 kv pairs = 32 B
        const int gr = row0 + lr;
        if (gr < N_NODES) {
            const unsigned short* Lk =
                (const unsigned short*)(Ls + lr * ELDS + c0);
            const unsigned short* Lv =
                (const unsigned short*)(Ls + 32 * ELDS + lr * ELDS + c0);
            u32x4 o0, o1;
#pragma unroll
            for (int q = 0; q < 4; ++q) {
                o0[q] = (unsigned)Lk[q] | ((unsigned)Lv[q] << 16);
                o1[q] = (unsigned)Lk[q + 4] | ((unsigned)Lv[q + 4] << 16);
            }
            unsigned int* kvp = (unsigned int*)kvb + (size_t)gr * 64 + c0;
            *(u32x4*)kvp = o0;
            *(u32x4*)(kvp + 4) = o1;
        }
    }
}

// layer-1: scatter blocks first, then gemm blocks (f32 x staged via LDS).
__global__ __launch_bounds__(256) void gemm1_scatter(
    const float* __restrict__ x, const bf16* __restrict__ wb,
    const float* __restrict__ bq, const float* __restrict__ bk,
    const float* __restrict__ bv, const float* __restrict__ bs,
    bf16* __restrict__ qb, bf16* __restrict__ kvb, bf16* __restrict__ sb,
    const int* __restrict__ ei,
    int* __restrict__ gcur, unsigned int* __restrict__ pairs) {
    __shared__ union {
        struct {
            int hist[256];
            int sm[256];
            int obs[NBK];
            unsigned int stage[EPB];
        } s;
        bf16 As[32 * ALDS];
    } u;

    const int t = threadIdx.x;

    if (blockIdx.x >= SCAT_BLKS) {
        const int blk = blockIdx.x - SCAT_BLKS;
        const int row0 = blk * 32;
        {
            const int r = t >> 3;
            const int c0 = (t & 7) << 4;
            int gr = row0 + r;
            if (gr >= N_NODES) gr = N_NODES - 1;
            const float* px = x + (size_t)gr * 128 + c0;
            f32x4 v0 = *(const f32x4*)px;
            f32x4 v1 = *(const f32x4*)(px + 4);
            f32x4 v2 = *(const f32x4*)(px + 8);
            f32x4 v3 = *(const f32x4*)(px + 12);
            bf16* dst = u.As + r * ALDS + c0;
            bf16x4 o0 = {f2b(v0[0]), f2b(v0[1]), f2b(v0[2]), f2b(v0[3])};
            bf16x4 o1 = {f2b(v1[0]), f2b(v1[1]), f2b(v1[2]), f2b(v1[3])};
            bf16x4 o2 = {f2b(v2[0]), f2b(v2[1]), f2b(v2[2]), f2b(v2[3])};
            bf16x4 o3 = {f2b(v3[0]), f2b(v3[1]), f2b(v3[2]), f2b(v3[3])};
            *(bf16x4*)(dst)      = o0;
            *(bf16x4*)(dst + 4)  = o1;
            *(bf16x4*)(dst + 8)  = o2;
            *(bf16x4*)(dst + 12) = o3;
        }
        __syncthreads();
        // epilogue reuses As as scratch (syncs internally before overwrite)
        gemm_body<128, true>(blk, t, u.As, u.As, wb, bq, bk, bv, bs,
                             qb, kvb, sb);
        return;
    }

    const int e0 = blockIdx.x * EPB;
    u.s.hist[t] = 0;
    __syncthreads();

    unsigned int pk[8];
    int bb[8], rr[8];
#pragma unroll
    for (int uu = 0; uu < 8; ++uu) {
        const int e = e0 + uu * 256 + t;
        if (e < N_EDGES) {
            int d  = ei[N_EDGES + e];
            int sv = ei[e];
            pk[uu] = ((unsigned int)d << 16) | (unsigned int)sv;
            bb[uu] = d >> 8;
            rr[uu] = atomicAdd(&u.s.hist[bb[uu]], 1);
        } else {
            bb[uu] = -1;
        }
    }
    __syncthreads();

    int hv = u.s.hist[t];
    u.s.sm[t] = hv;
    __syncthreads();
    for (int st = 1; st < 256; st <<= 1) {
        int tmp = (t >= st) ? u.s.sm[t - st] : 0;
        __syncthreads();
        u.s.sm[t] += tmp;
        __syncthreads();
    }
    const int total = u.s.sm[255];

    if (t < NBK && hv > 0) {
        int g = atomicAdd(&gcur[t * CURSTRIDE], hv);
        u.s.obs[t] = t * CAP + g - (u.s.sm[t] - hv);
    }
    __syncthreads();

#pragma unroll
    for (int uu = 0; uu < 8; ++uu)
        if (bb[uu] >= 0)
            u.s.stage[(u.s.sm[bb[uu]] - u.s.hist[bb[uu]]) + rr[uu]] = pk[uu];
    __syncthreads();

    for (int j = t; j < total; j += 256) {
        unsigned int pr = u.s.stage[j];
        int b = pr >> 24;
        int pos = u.s.obs[b] + j;
        if (pos - b * CAP < CAP)
            pairs[pos] = pr;
    }
}

// Pass B: one block per bucket; single window read into registers.
__global__ __launch_bounds__(256) void passB(const int* __restrict__ gcur,
                                             const unsigned int* __restrict__ pairs,
                                             unsigned short* __restrict__ csr,
                                             int* __restrict__ off) {
    __shared__ int bsm[256];
    __shared__ int cnt[256];
    __shared__ int pfx[256];
    __shared__ int place[256];
    const int b = blockIdx.x;
    const int t = threadIdx.x;
    const int n0 = b << 8;
    const int nb = ((n0 + 256 < N_NODES) ? 256 : N_NODES - n0);

    int gv = (t < NBK) ? gcur[t * CURSTRIDE] : 0;
    bsm[t] = (t < b) ? gv : 0;
    cnt[t] = 0;
    place[t] = 0;
    __syncthreads();
    for (int st = 128; st >= 1; st >>= 1) {
        if (t < st) bsm[t] += bsm[t + st];
        __syncthreads();
    }
    const int base = bsm[0];
    const int myCnt = gcur[b * CURSTRIDE];
    const unsigned int* win = pairs + (size_t)b * CAP;

    unsigned int pr[CAPT];
    int held = 0;
    for (int j = t; j < myCnt; j += 256) pr[held++] = win[j];

    for (int k = 0; k < held; ++k)
        atomicAdd(&cnt[(pr[k] >> 16) - n0], 1);
    __syncthreads();

    int cv = cnt[t];
    pfx[t] = cv;
    __syncthreads();
    for (int st = 1; st < 256; st <<= 1) {
        int tmp = (t >= st) ? pfx[t - st] : 0;
        __syncthreads();
        pfx[t] += tmp;
        __syncthreads();
    }
    const int excl = pfx[t] - cv;

    if (t < nb) off[n0 + t] = base + excl;
    if (b == NBK - 1 && t == 0) off[N_NODES] = base + myCnt;

    for (int k = 0; k < held; ++k) {
        unsigned int p = pr[k];
        int i = (int)(p >> 16) - n0;
        int r = atomicAdd(&place[i], 1);
        csr[base + (pfx[i] - cnt[i]) + r] = (unsigned short)(p & 0xffffu);
    }
}

__global__ __launch_bounds__(256) void gemm2(
    const bf16* __restrict__ A, const bf16* __restrict__ wb,
    const float* __restrict__ bq, const float* __restrict__ bk,
    const float* __restrict__ bv, const float* __restrict__ bs,
    bf16* __restrict__ qb, bf16* __restrict__ kvb, bf16* __restrict__ sb) {
    __shared__ bf16 Ls[32 * ELDS * 2];
    gemm_body<64, false>(blockIdx.x, threadIdx.x, Ls, A, wb,
                         bq, bk, bv, bs, qb, kvb, sb);
}

// ---- Aggregation: 4 edge-slots/wave, 16 lanes/slot, 4 dims/lane.
// Main loop: 4 gather batches (16 edges) in flight for MLP. ----
template <int H, bool RELU, typename OT>
__global__ __launch_bounds__(256) void agg_csr(const int* __restrict__ off,
                                               const unsigned short* __restrict__ csr_src,
                                               const bf16* __restrict__ qb,
                                               const unsigned int* __restrict__ kvu,
                                               const bf16* __restrict__ sb,
                                               OT* __restrict__ out) {
    const float SC = ((H == 4) ? 0.25f : 0.125f) * 1.4426950408889634f;
    const int lane = threadIdx.x & 63;
    const int slot = lane >> 4;
    const int m    = lane & 15;
    const int n = (blockIdx.x * 256 + threadIdx.x) >> 6;
    if (n >= N_NODES) return;

    const unsigned int* qp = (const unsigned int*)qb + (size_t)n * 32 + m * 2;
    const unsigned int q01 = qp[0], q23 = qp[1];
    const float qf0 = lo_f(q01), qf1 = hi_f(q01);
    const float qf2 = lo_f(q23), qf3 = hi_f(q23);

    float a0 = 0.f, a1 = 0.f, a2 = 0.f, a3 = 0.f, ds = 0.f;
    int jb = off[n];
    const int j1 = off[n + 1];
    const unsigned int mb = (unsigned)m * 4;

    // main: 4 batches (16 edges) in flight per iter
    for (; jb + 16 <= j1; jb += 16) {
        unsigned s[4];
#pragma unroll
        for (int bch = 0; bch < 4; ++bch)
            s[bch] = (unsigned)csr_src[jb + bch * 4 + slot];
        u32x4 w[4];
#pragma unroll
        for (int bch = 0; bch < 4; ++bch)
            w[bch] = *(const u32x4*)(kvu + (((size_t)s[bch]) << 6) + mb);
        float p[4];
#pragma unroll
        for (int bch = 0; bch < 4; ++bch) {
            float pp = qf0 * lo_f(w[bch][0]);
            pp = fmaf(qf1, lo_f(w[bch][1]), pp);
            pp = fmaf(qf2, lo_f(w[bch][2]), pp);
            pp = fmaf(qf3, lo_f(w[bch][3]), pp);
            p[bch] = pp;
        }
#pragma unroll
        for (int bch = 0; bch < 4; ++bch) p[bch] = edge_reduce<H>(p[bch]);
#pragma unroll
        for (int bch = 0; bch < 4; ++bch) {
            const float e = exp2f(p[bch] * SC);
            a0 = fmaf(e, hi_f(w[bch][0]), a0);
            a1 = fmaf(e, hi_f(w[bch][1]), a1);
            a2 = fmaf(e, hi_f(w[bch][2]), a2);
            a3 = fmaf(e, hi_f(w[bch][3]), a3);
            ds += e;
        }
    }
    // mid: 8-edge batches
    for (; jb + 8 <= j1; jb += 8) {
        const unsigned s0 = (unsigned)csr_src[jb + slot];
        const unsigned s1 = (unsigned)csr_src[jb + 4 + slot];
        u32x4 w0 = *(const u32x4*)(kvu + (((size_t)s0) << 6) + mb);
        u32x4 w1 = *(const u32x4*)(kvu + (((size_t)s1) << 6) + mb);
        float p0 = qf0 * lo_f(w0[0]);
        p0 = fmaf(qf1, lo_f(w0[1]), p0);
        p0 = fmaf(qf2, lo_f(w0[2]), p0);
        p0 = fmaf(qf3, lo_f(w0[3]), p0);
        float p1 = qf0 * lo_f(w1[0]);
        p1 = fmaf(qf1, lo_f(w1[1]), p1);
        p1 = fmaf(qf2, lo_f(w1[2]), p1);
        p1 = fmaf(qf3, lo_f(w1[3]), p1);
        p0 = edge_reduce<H>(p0);
        p1 = edge_reduce<H>(p1);
        const float e0 = exp2f(p0 * SC);
        const float e1 = exp2f(p1 * SC);
        a0 = fmaf(e0, hi_f(w0[0]), a0); a0 = fmaf(e1, hi_f(w1[0]), a0);
        a1 = fmaf(e0, hi_f(w0[1]), a1); a1 = fmaf(e1, hi_f(w1[1]), a1);
        a2 = fmaf(e0, hi_f(w0[2]), a2); a2 = fmaf(e1, hi_f(w1[2]), a2);
        a3 = fmaf(e0, hi_f(w0[3]), a3); a3 = fmaf(e1, hi_f(w1[3]), a3);
        ds += e0 + e1;
    }
    // tail: masked 4-edge batches
    for (; jb < j1; jb += 4) {
        int jc = jb + slot;
        const bool valid = jc < j1;
        if (!valid) jc = j1 - 1;
        const unsigned s0 = (unsigned)csr_src[jc];
        u32x4 w0 = *(const u32x4*)(kvu + (((size_t)s0) << 6) + mb);
        float p0 = qf0 * lo_f(w0[0]);
        p0 = fmaf(qf1, lo_f(w0[1]), p0);
        p0 = fmaf(qf2, lo_f(w0[2]), p0);
        p0 = fmaf(qf3, lo_f(w0[3]), p0);
        p0 = edge_reduce<H>(p0);
        const float e0 = valid ? exp2f(p0 * SC) : 0.f;
        a0 = fmaf(e0, hi_f(w0[0]), a0);
        a1 = fmaf(e0, hi_f(w0[1]), a1);
        a2 = fmaf(e0, hi_f(w0[2]), a2);
        a3 = fmaf(e0, hi_f(w0[3]), a3);
        ds += e0;
    }

    a0 += __shfl_xor(a0, 16, 64); a0 += __shfl_xor(a0, 32, 64);
    a1 += __shfl_xor(a1, 16, 64); a1 += __shfl_xor(a1, 32, 64);
    a2 += __shfl_xor(a2, 16, 64); a2 += __shfl_xor(a2, 32, 64);
    a3 += __shfl_xor(a3, 16, 64); a3 += __shfl_xor(a3, 32, 64);
    ds += __shfl_xor(ds, 16, 64); ds += __shfl_xor(ds, 32, 64);

    if (lane < 16) {
        const float inv = (ds != 0.f) ? 1.f / ds : 0.f;
        const unsigned int* sp = (const unsigned int*)sb + (size_t)n * 32 + m * 2;
        const unsigned int s01 = sp[0], s23 = sp[1];
        float v0 = fmaf(a0, inv, lo_f(s01));
        float v1 = fmaf(a1, inv, hi_f(s01));
        float v2 = fmaf(a2, inv, lo_f(s23));
        float v3 = fmaf(a3, inv, hi_f(s23));
        if (RELU) {
            v0 = fmaxf(v0, 0.f); v1 = fmaxf(v1, 0.f);
            v2 = fmaxf(v2, 0.f); v3 = fmaxf(v3, 0.f);
        }
        if constexpr (__hip_internal::is_same<OT, bf16>::value) {
            u32x2 o;
            o[0] = (unsigned)(unsigned short)f2b(v0) |
                   ((unsigned)(unsigned short)f2b(v1) << 16);
            o[1] = (unsigned)(unsigned short)f2b(v2) |
                   ((unsigned)(unsigned short)f2b(v3) << 16);
            *(u32x2*)((unsigned int*)out + (size_t)n * 32 + m * 2) = o;  // hb
        } else {
            f32x4 o = (f32x4){v0, v1, v2, v3};
            __builtin_nontemporal_store(o, (f32x4*)((float*)out + (size_t)n * 64 + m * 4));
        }
    }
}

extern "C" void kernel_launch(void* const* d_in, const int* in_sizes, int n_in,
                              void* d_out, int out_size, void* d_ws, size_t ws_size,
                              hipStream_t stream) {
    const float* x  = (const float*)d_in[0];
    const int*   ei = (const int*)d_in[1];
    const float* bq1 = (const float*)d_in[3];
    const float* bk1 = (const float*)d_in[5];
    const float* bv1 = (const float*)d_in[7];
    const float* bs1 = (const float*)d_in[9];
    const float* bq2 = (const float*)d_in[11];
    const float* bk2 = (const float*)d_in[13];
    const float* bv2 = (const float*)d_in[15];
    const float* bs2 = (const float*)d_in[17];

    WPtrs wp;
    wp.p[0] = (const float*)d_in[2];
    wp.p[1] = (const float*)d_in[4];
    wp.p[2] = (const float*)d_in[6];
    wp.p[3] = (const float*)d_in[8];
    wp.p[4] = (const float*)d_in[10];
    wp.p[5] = (const float*)d_in[12];
    wp.p[6] = (const float*)d_in[14];
    wp.p[7] = (const float*)d_in[16];

    const size_t N = N_NODES;
    bf16* hb  = (bf16*)d_ws;                 // NPAD*64
    bf16* qb  = hb + (size_t)NPAD * 64;      // N*64
    bf16* kvb = qb + N * 64;                 // 2*N*64 interleaved
    bf16* wb  = kvb + 2 * N * 64;            // 49152
    bf16* sb  = wb + 49152;                  // N*64 (bf16)
    int* off  = (int*)(sb + N * 64);         // N+1
    int* gcur = off + N_NODES + 1;           // NBK*CURSTRIDE
    unsigned short* csr = (unsigned short*)(gcur + NBK * CURSTRIDE); // E u16
    unsigned int* pairs = (unsigned int*)(csr + N_EDGES);            // NBK*CAP

    const int aggGrid = (N_NODES * 64 + 255) / 256;

    // ---------------- prep (w-conv + gcur zero; tiny) ----------------
    prep<<<64, 256, 0, stream>>>(wp, wb, gcur);

    // ---------------- Layer 1 (scatter-first + gemm w/ LDS-staged x) -------
    gemm1_scatter<<<GEMM_BLKS + SCAT_BLKS, 256, 0, stream>>>(
        x, wb, bq1, bk1, bv1, bs1, qb, kvb, sb, ei, gcur, pairs);
    passB<<<NBK, 256, 0, stream>>>(gcur, pairs, csr, off);
    agg_csr<4, true, bf16><<<aggGrid, 256, 0, stream>>>(off, csr, qb,
                                                        (const unsigned int*)kvb, sb, hb);

    // ---------------- Layer 2 ----------------
    gemm2<<<GEMM_BLKS, 256, 0, stream>>>(hb, wb + 32768, bq2, bk2, bv2, bs2,
                                         qb, kvb, sb);
    agg_csr<1, false, float><<<aggGrid, 256, 0, stream>>>(off, csr, qb,
                                                          (const unsigned int*)kvb, sb,
                                                          (float*)d_out);
}

// Round 17
// 220.669 us; speedup vs baseline: 1.1233x; 1.0068x over previous
//
#include <hip/hip_runtime.h>
#include <hip/hip_bf16.h>

// ROUND 32. r31 WIN (222.2, -13us: store-packing theory confirmed).
// Budget closes only with TWO 262MB harness fills/iter (86us fixed):
// 86 fill + agg 72 (PROVEN floor, 5.7 TB/s service) + gemm1_scatter ~30 +
// passB 9 + gemm2 ~8 + prep 2 + gaps ~15 = 222. Last structural slack:
// passB runs 196 blocks = 24% CU util. Change: passB 512 threads/block --
// halves window-read + count/place serial work (csr order per node is
// irrelevant, sum commutes). Predict passB 9 -> ~5-6, total -> ~217-220.
// If <2us: every dispatch at demonstrated floor -> declare ROOFLINE.

#define N_NODES 50000
#define N_EDGES 800000
#define NPAD    50048
#define GEMM_BLKS 1563 // ceil(50000/32), 32-row tiles
#define EPB 2048       // edges per scatter block
#define SCAT_BLKS 391  // ceil(800000/2048)
#define NBK 196        // buckets of 256 nodes (dst>>8)
#define CAP 6144       // fixed pairs window per bucket
#define CAPT 12        // ceil(CAP/512) per-thread reg hold in passB
#define CURSTRIDE 16   // one cursor per 64B line
#define ALDS 132       // padded LDS row stride (bf16 units), As = 32*132 = 4224
#define ELDS 66        // epilogue LDS row stride (bf16 units), 2 mats x 32*66 = 4224

using bf16 = __hip_bfloat16;
typedef __attribute__((ext_vector_type(8))) short bf16x8;
typedef __attribute__((ext_vector_type(4))) short bf16x4;
typedef __attribute__((ext_vector_type(4))) float f32x4;
typedef __attribute__((ext_vector_type(4))) unsigned int u32x4;
typedef __attribute__((ext_vector_type(2))) unsigned int u32x2;

__device__ __forceinline__ float b2f(unsigned short u) {
    unsigned int x = ((unsigned int)u) << 16;
    return __builtin_bit_cast(float, x);
}
__device__ __forceinline__ float lo_f(unsigned int u) {
    return __builtin_bit_cast(float, u << 16);
}
__device__ __forceinline__ float hi_f(unsigned int u) {
    return __builtin_bit_cast(float, u & 0xffff0000u);
}
__device__ __forceinline__ short f2b(float f) {
    return (short)__builtin_bit_cast(unsigned short, __float2bfloat16(f));
}

// DPP add helpers (verified on HW r24/r25).
template <int CTRL>
__device__ __forceinline__ float dadd(float p) {
    int vi = __builtin_bit_cast(int, p);
    int mv = __builtin_amdgcn_update_dpp(vi, vi, CTRL, 0xF, 0xF, false);
    return p + __builtin_bit_cast(float, mv);
}
template <int H>
__device__ __forceinline__ float edge_reduce(float p) {
    p = dadd<0xB1>(p);
    p = dadd<0x4E>(p);
    if constexpr (H == 1) {
        p = dadd<0x124>(p);  // row_ror:4
        p = dadd<0x128>(p);  // row_ror:8
    }
    return p;
}

struct WPtrs { const float* p[8]; };

// ---------------- prep: conv_w + gcur zero (tiny) ----------------
__global__ __launch_bounds__(256) void prep(WPtrs wp, bf16* __restrict__ wb,
                                            int* __restrict__ gcur) {
    const int gs = gridDim.x * 256;
    const int t0 = blockIdx.x * 256 + threadIdx.x;
    if (t0 < NBK * CURSTRIDE) gcur[t0] = 0;
    for (int i = t0; i < 49152; i += gs) {
        int y, o;
        if (i < 32768) { y = i >> 13; o = i & 8191; }
        else { y = 4 + ((i - 32768) >> 12); o = (i - 32768) & 4095; }
        wb[i] = __float2bfloat16(wp.p[y][o]);
    }
}

// ------------- MFMA GEMM body (32-row tile, 4 weight mats) -------------
// Ls: 4224-bf16 LDS scratch for the packed epilogue (may alias the A-tile
// for LDSA=true; epilogue syncs before overwriting).
template <int K, bool LDSA>
__device__ __forceinline__ void gemm_body(
    int blk, int tid, bf16* __restrict__ Ls,
    const bf16* __restrict__ A, const bf16* __restrict__ wb,
    const float* __restrict__ bq, const float* __restrict__ bk,
    const float* __restrict__ bv, const float* __restrict__ bs,
    bf16* __restrict__ qb, bf16* __restrict__ kvb, bf16* __restrict__ sb) {
    const int wave = tid >> 6;
    const int lane = tid & 63;
    const int row0 = blk * 32;
    const int m  = lane & 15;
    const int kg = lane >> 4;
    const bf16* W = wb + (size_t)wave * 64 * K;

    f32x4 acc[2][4];
#pragma unroll
    for (int i = 0; i < 2; ++i)
#pragma unroll
        for (int j = 0; j < 4; ++j) acc[i][j] = (f32x4){0.f, 0.f, 0.f, 0.f};

#pragma unroll
    for (int k0 = 0; k0 < K; k0 += 32) {
        bf16x8 a[2], b[4];
#pragma unroll
        for (int i = 0; i < 2; ++i) {
            if constexpr (LDSA) {
                const bf16* ap = A + (size_t)(i * 16 + m) * ALDS + k0 + kg * 8;
                bf16x4 lo = *(const bf16x4*)ap;
                bf16x4 hi = *(const bf16x4*)(ap + 4);
#pragma unroll
                for (int q = 0; q < 4; ++q) { a[i][q] = lo[q]; a[i][q + 4] = hi[q]; }
            } else {
                a[i] = *(const bf16x8*)(A + (size_t)(row0 + i * 16 + m) * K + k0 + kg * 8);
            }
        }
#pragma unroll
        for (int j = 0; j < 4; ++j)
            b[j] = *(const bf16x8*)(W + (size_t)(j * 16 + m) * K + k0 + kg * 8);
#pragma unroll
        for (int i = 0; i < 2; ++i)
#pragma unroll
            for (int j = 0; j < 4; ++j)
                acc[i][j] = __builtin_amdgcn_mfma_f32_16x16x32_bf16(a[i], b[j], acc[i][j], 0, 0, 0);
    }

    const int crow = (lane >> 4) * 4;
    const int ccol = lane & 15;
    const float* B = (wave == 0) ? bq : (wave == 1) ? bk : (wave == 2) ? bv : bs;
    float bias[4];
#pragma unroll
    for (int j = 0; j < 4; ++j) bias[j] = B[j * 16 + ccol];
#pragma unroll
    for (int i = 0; i < 2; ++i)
#pragma unroll
        for (int j = 0; j < 4; ++j)
#pragma unroll
            for (int r = 0; r < 4; ++r) acc[i][j][r] += bias[j];

    // ---- packed epilogue: LDS transpose -> 4x16B coalesced stores ----
    __syncthreads();  // k-loop LDS reads done (LDSA); waves aligned

    // pass A: q (wave0) -> Ls[0], s (wave3) -> Ls[2112]
    {
        bf16* dst = (wave == 0) ? Ls : (wave == 3) ? Ls + 32 * ELDS : nullptr;
        if (dst) {
#pragma unroll
            for (int i = 0; i < 2; ++i)
#pragma unroll
                for (int r = 0; r < 4; ++r) {
                    const int lr = i * 16 + crow + r;
#pragma unroll
                    for (int j = 0; j < 4; ++j)
                        dst[lr * ELDS + j * 16 + ccol] =
                            __float2bfloat16(acc[i][j][r]);
                }
        }
    }
    __syncthreads();
    {
        const int lr = tid >> 3;
        const int c0 = (tid & 7) << 3;
        const int gr = row0 + lr;
        if (gr < N_NODES) {
            const bf16* Lq = Ls + lr * ELDS + c0;
            const bf16* Lss = Ls + 32 * ELDS + lr * ELDS + c0;
            bf16x4 q0 = *(const bf16x4*)Lq;
            bf16x4 q1 = *(const bf16x4*)(Lq + 4);
            bf16x4 s0 = *(const bf16x4*)Lss;
            bf16x4 s1 = *(const bf16x4*)(Lss + 4);
            bf16x8 qv, sv;
#pragma unroll
            for (int q = 0; q < 4; ++q) {
                qv[q] = q0[q]; qv[q + 4] = q1[q];
                sv[q] = s0[q]; sv[q + 4] = s1[q];
            }
            *(bf16x8*)(qb + (size_t)gr * 64 + c0) = qv;
            *(bf16x8*)(sb + (size_t)gr * 64 + c0) = sv;
        }
    }
    __syncthreads();
    // pass B: k (wave1) -> Ls[0], v (wave2) -> Ls[2112]
    {
        bf16* dst = (wave == 1) ? Ls : (wave == 2) ? Ls + 32 * ELDS : nullptr;
        if (dst) {
#pragma unroll
            for (int i = 0; i < 2; ++i)
#pragma unroll
                for (int r = 0; r < 4; ++r) {
                    const int lr = i * 16 + crow + r;
#pragma unroll
                    for (int j = 0; j < 4; ++j)
                        dst[lr * ELDS + j * 16 + ccol] =
                            __float2bfloat16(acc[i][j][r]);
                }
        }
    }
    __syncthreads();
    {
        const int lr = tid >> 3;
        const int c0 = (tid & 7) << 3;  // 8 kv pairs = 32 B
        const int gr = row0 + lr;
        if (gr < N_NODES) {
            const unsigned short* Lk =
                (const unsigned short*)(Ls + lr * ELDS + c0);
            const unsigned short* Lv =
                (const unsigned short*)(Ls + 32 * ELDS + lr * ELDS + c0);
            u32x4 o0, o1;
#pragma unroll
            for (int q = 0; q < 4; ++q) {
                o0[q] = (unsigned)Lk[q] | ((unsigned)Lv[q] << 16);
                o1[q] = (unsigned)Lk[q + 4] | ((unsigned)Lv[q + 4] << 16);
            }
            unsigned int* kvp = (unsigned int*)kvb + (size_t)gr * 64 + c0;
            *(u32x4*)kvp = o0;
            *(u32x4*)(kvp + 4) = o1;
        }
    }
}

// layer-1: scatter blocks first, then gemm blocks (f32 x staged via LDS).
__global__ __launch_bounds__(256) void gemm1_scatter(
    const float* __restrict__ x, const bf16* __restrict__ wb,
    const float* __restrict__ bq, const float* __restrict__ bk,
    const float* __restrict__ bv, const float* __restrict__ bs,
    bf16* __restrict__ qb, bf16* __restrict__ kvb, bf16* __restrict__ sb,
    const int* __restrict__ ei,
    int* __restrict__ gcur, unsigned int* __restrict__ pairs) {
    __shared__ union {
        struct {
            int hist[256];
            int sm[256];
            int obs[NBK];
            unsigned int stage[EPB];
        } s;
        bf16 As[32 * ALDS];
    } u;

    const int t = threadIdx.x;

    if (blockIdx.x >= SCAT_BLKS) {
        const int blk = blockIdx.x - SCAT_BLKS;
        const int row0 = blk * 32;
        {
            const int r = t >> 3;
            const int c0 = (t & 7) << 4;
            int gr = row0 + r;
            if (gr >= N_NODES) gr = N_NODES - 1;
            const float* px = x + (size_t)gr * 128 + c0;
            f32x4 v0 = *(const f32x4*)px;
            f32x4 v1 = *(const f32x4*)(px + 4);
            f32x4 v2 = *(const f32x4*)(px + 8);
            f32x4 v3 = *(const f32x4*)(px + 12);
            bf16* dst = u.As + r * ALDS + c0;
            bf16x4 o0 = {f2b(v0[0]), f2b(v0[1]), f2b(v0[2]), f2b(v0[3])};
            bf16x4 o1 = {f2b(v1[0]), f2b(v1[1]), f2b(v1[2]), f2b(v1[3])};
            bf16x4 o2 = {f2b(v2[0]), f2b(v2[1]), f2b(v2[2]), f2b(v2[3])};
            bf16x4 o3 = {f2b(v3[0]), f2b(v3[1]), f2b(v3[2]), f2b(v3[3])};
            *(bf16x4*)(dst)      = o0;
            *(bf16x4*)(dst + 4)  = o1;
            *(bf16x4*)(dst + 8)  = o2;
            *(bf16x4*)(dst + 12) = o3;
        }
        __syncthreads();
        // epilogue reuses As as scratch (syncs internally before overwrite)
        gemm_body<128, true>(blk, t, u.As, u.As, wb, bq, bk, bv, bs,
                             qb, kvb, sb);
        return;
    }

    const int e0 = blockIdx.x * EPB;
    u.s.hist[t] = 0;
    __syncthreads();

    unsigned int pk[8];
    int bb[8], rr[8];
#pragma unroll
    for (int uu = 0; uu < 8; ++uu) {
        const int e = e0 + uu * 256 + t;
        if (e < N_EDGES) {
            int d  = ei[N_EDGES + e];
            int sv = ei[e];
            pk[uu] = ((unsigned int)d << 16) | (unsigned int)sv;
            bb[uu] = d >> 8;
            rr[uu] = atomicAdd(&u.s.hist[bb[uu]], 1);
        } else {
            bb[uu] = -1;
        }
    }
    __syncthreads();

    int hv = u.s.hist[t];
    u.s.sm[t] = hv;
    __syncthreads();
    for (int st = 1; st < 256; st <<= 1) {
        int tmp = (t >= st) ? u.s.sm[t - st] : 0;
        __syncthreads();
        u.s.sm[t] += tmp;
        __syncthreads();
    }
    const int total = u.s.sm[255];

    if (t < NBK && hv > 0) {
        int g = atomicAdd(&gcur[t * CURSTRIDE], hv);
        u.s.obs[t] = t * CAP + g - (u.s.sm[t] - hv);
    }
    __syncthreads();

#pragma unroll
    for (int uu = 0; uu < 8; ++uu)
        if (bb[uu] >= 0)
            u.s.stage[(u.s.sm[bb[uu]] - u.s.hist[bb[uu]]) + rr[uu]] = pk[uu];
    __syncthreads();

    for (int j = t; j < total; j += 256) {
        unsigned int pr = u.s.stage[j];
        int b = pr >> 24;
        int pos = u.s.obs[b] + j;
        if (pos - b * CAP < CAP)
            pairs[pos] = pr;
    }
}

// Pass B: one 512-thread block per bucket; single window read into regs.
// csr order within a node's segment is irrelevant (sum commutes).
__global__ __launch_bounds__(512) void passB(const int* __restrict__ gcur,
                                             const unsigned int* __restrict__ pairs,
                                             unsigned short* __restrict__ csr,
                                             int* __restrict__ off) {
    __shared__ int bsm[256];
    __shared__ int cnt[256];
    __shared__ int pfx[256];
    __shared__ int place[256];
    const int b = blockIdx.x;
    const int t = threadIdx.x;
    const int n0 = b << 8;
    const int nb = ((n0 + 256 < N_NODES) ? 256 : N_NODES - n0);

    if (t < 256) {
        int gv = (t < NBK) ? gcur[t * CURSTRIDE] : 0;
        bsm[t] = (t < b) ? gv : 0;
        cnt[t] = 0;
        place[t] = 0;
    }
    __syncthreads();
    for (int st = 128; st >= 1; st >>= 1) {
        if (t < st) bsm[t] += bsm[t + st];
        __syncthreads();
    }
    const int base = bsm[0];
    const int myCnt = gcur[b * CURSTRIDE];
    const unsigned int* win = pairs + (size_t)b * CAP;

    unsigned int pr[CAPT];
    int held = 0;
    for (int j = t; j < myCnt; j += 512) pr[held++] = win[j];

    for (int k = 0; k < held; ++k)
        atomicAdd(&cnt[(pr[k] >> 16) - n0], 1);
    __syncthreads();

    if (t < 256) pfx[t] = cnt[t];
    __syncthreads();
    for (int st = 1; st < 256; st <<= 1) {
        int tmp = (t < 256 && t >= st) ? pfx[t - st] : 0;
        __syncthreads();
        if (t < 256) pfx[t] += tmp;
        __syncthreads();
    }

    if (t < nb) off[n0 + t] = base + (pfx[t] - cnt[t]);
    if (b == NBK - 1 && t == 0) off[N_NODES] = base + myCnt;

    for (int k = 0; k < held; ++k) {
        unsigned int p = pr[k];
        int i = (int)(p >> 16) - n0;
        int r = atomicAdd(&place[i], 1);
        csr[base + (pfx[i] - cnt[i]) + r] = (unsigned short)(p & 0xffffu);
    }
}

__global__ __launch_bounds__(256) void gemm2(
    const bf16* __restrict__ A, const bf16* __restrict__ wb,
    const float* __restrict__ bq, const float* __restrict__ bk,
    const float* __restrict__ bv, const float* __restrict__ bs,
    bf16* __restrict__ qb, bf16* __restrict__ kvb, bf16* __restrict__ sb) {
    __shared__ bf16 Ls[32 * ELDS * 2];
    gemm_body<64, false>(blockIdx.x, threadIdx.x, Ls, A, wb,
                         bq, bk, bv, bs, qb, kvb, sb);
}

// ---- Aggregation: 4 edge-slots/wave, 16 lanes/slot, 4 dims/lane.
// Main loop: 4 gather batches (16 edges) in flight for MLP. ----
template <int H, bool RELU, typename OT>
__global__ __launch_bounds__(256) void agg_csr(const int* __restrict__ off,
                                               const unsigned short* __restrict__ csr_src,
                                               const bf16* __restrict__ qb,
                                               const unsigned int* __restrict__ kvu,
                                               const bf16* __restrict__ sb,
                                               OT* __restrict__ out) {
    const float SC = ((H == 4) ? 0.25f : 0.125f) * 1.4426950408889634f;
    const int lane = threadIdx.x & 63;
    const int slot = lane >> 4;
    const int m    = lane & 15;
    const int n = (blockIdx.x * 256 + threadIdx.x) >> 6;
    if (n >= N_NODES) return;

    const unsigned int* qp = (const unsigned int*)qb + (size_t)n * 32 + m * 2;
    const unsigned int q01 = qp[0], q23 = qp[1];
    const float qf0 = lo_f(q01), qf1 = hi_f(q01);
    const float qf2 = lo_f(q23), qf3 = hi_f(q23);

    float a0 = 0.f, a1 = 0.f, a2 = 0.f, a3 = 0.f, ds = 0.f;
    int jb = off[n];
    const int j1 = off[n + 1];
    const unsigned int mb = (unsigned)m * 4;

    // main: 4 batches (16 edges) in flight per iter
    for (; jb + 16 <= j1; jb += 16) {
        unsigned s[4];
#pragma unroll
        for (int bch = 0; bch < 4; ++bch)
            s[bch] = (unsigned)csr_src[jb + bch * 4 + slot];
        u32x4 w[4];
#pragma unroll
        for (int bch = 0; bch < 4; ++bch)
            w[bch] = *(const u32x4*)(kvu + (((size_t)s[bch]) << 6) + mb);
        float p[4];
#pragma unroll
        for (int bch = 0; bch < 4; ++bch) {
            float pp = qf0 * lo_f(w[bch][0]);
            pp = fmaf(qf1, lo_f(w[bch][1]), pp);
            pp = fmaf(qf2, lo_f(w[bch][2]), pp);
            pp = fmaf(qf3, lo_f(w[bch][3]), pp);
            p[bch] = pp;
        }
#pragma unroll
        for (int bch = 0; bch < 4; ++bch) p[bch] = edge_reduce<H>(p[bch]);
#pragma unroll
        for (int bch = 0; bch < 4; ++bch) {
            const float e = exp2f(p[bch] * SC);
            a0 = fmaf(e, hi_f(w[bch][0]), a0);
            a1 = fmaf(e, hi_f(w[bch][1]), a1);
            a2 = fmaf(e, hi_f(w[bch][2]), a2);
            a3 = fmaf(e, hi_f(w[bch][3]), a3);
            ds += e;
        }
    }
    // mid: 8-edge batches
    for (; jb + 8 <= j1; jb += 8) {
        const unsigned s0 = (unsigned)csr_src[jb + slot];
        const unsigned s1 = (unsigned)csr_src[jb + 4 + slot];
        u32x4 w0 = *(const u32x4*)(kvu + (((size_t)s0) << 6) + mb);
        u32x4 w1 = *(const u32x4*)(kvu + (((size_t)s1) << 6) + mb);
        float p0 = qf0 * lo_f(w0[0]);
        p0 = fmaf(qf1, lo_f(w0[1]), p0);
        p0 = fmaf(qf2, lo_f(w0[2]), p0);
        p0 = fmaf(qf3, lo_f(w0[3]), p0);
        float p1 = qf0 * lo_f(w1[0]);
        p1 = fmaf(qf1, lo_f(w1[1]), p1);
        p1 = fmaf(qf2, lo_f(w1[2]), p1);
        p1 = fmaf(qf3, lo_f(w1[3]), p1);
        p0 = edge_reduce<H>(p0);
        p1 = edge_reduce<H>(p1);
        const float e0 = exp2f(p0 * SC);
        const float e1 = exp2f(p1 * SC);
        a0 = fmaf(e0, hi_f(w0[0]), a0); a0 = fmaf(e1, hi_f(w1[0]), a0);
        a1 = fmaf(e0, hi_f(w0[1]), a1); a1 = fmaf(e1, hi_f(w1[1]), a1);
        a2 = fmaf(e0, hi_f(w0[2]), a2); a2 = fmaf(e1, hi_f(w1[2]), a2);
        a3 = fmaf(e0, hi_f(w0[3]), a3); a3 = fmaf(e1, hi_f(w1[3]), a3);
        ds += e0 + e1;
    }
    // tail: masked 4-edge batches
    for (; jb < j1; jb += 4) {
        int jc = jb + slot;
        const bool valid = jc < j1;
        if (!valid) jc = j1 - 1;
        const unsigned s0 = (unsigned)csr_src[jc];
        u32x4 w0 = *(const u32x4*)(kvu + (((size_t)s0) << 6) + mb);
        float p0 = qf0 * lo_f(w0[0]);
        p0 = fmaf(qf1, lo_f(w0[1]), p0);
        p0 = fmaf(qf2, lo_f(w0[2]), p0);
        p0 = fmaf(qf3, lo_f(w0[3]), p0);
        p0 = edge_reduce<H>(p0);
        const float e0 = valid ? exp2f(p0 * SC) : 0.f;
        a0 = fmaf(e0, hi_f(w0[0]), a0);
        a1 = fmaf(e0, hi_f(w0[1]), a1);
        a2 = fmaf(e0, hi_f(w0[2]), a2);
        a3 = fmaf(e0, hi_f(w0[3]), a3);
        ds += e0;
    }

    a0 += __shfl_xor(a0, 16, 64); a0 += __shfl_xor(a0, 32, 64);
    a1 += __shfl_xor(a1, 16, 64); a1 += __shfl_xor(a1, 32, 64);
    a2 += __shfl_xor(a2, 16, 64); a2 += __shfl_xor(a2, 32, 64);
    a3 += __shfl_xor(a3, 16, 64); a3 += __shfl_xor(a3, 32, 64);
    ds += __shfl_xor(ds, 16, 64); ds += __shfl_xor(ds, 32, 64);

    if (lane < 16) {
        const float inv = (ds != 0.f) ? 1.f / ds : 0.f;
        const unsigned int* sp = (const unsigned int*)sb + (size_t)n * 32 + m * 2;
        const unsigned int s01 = sp[0], s23 = sp[1];
        float v0 = fmaf(a0, inv, lo_f(s01));
        float v1 = fmaf(a1, inv, hi_f(s01));
        float v2 = fmaf(a2, inv, lo_f(s23));
        float v3 = fmaf(a3, inv, hi_f(s23));
        if (RELU) {
            v0 = fmaxf(v0, 0.f); v1 = fmaxf(v1, 0.f);
            v2 = fmaxf(v2, 0.f); v3 = fmaxf(v3, 0.f);
        }
        if constexpr (__hip_internal::is_same<OT, bf16>::value) {
            u32x2 o;
            o[0] = (unsigned)(unsigned short)f2b(v0) |
                   ((unsigned)(unsigned short)f2b(v1) << 16);
            o[1] = (unsigned)(unsigned short)f2b(v2) |
                   ((unsigned)(unsigned short)f2b(v3) << 16);
            *(u32x2*)((unsigned int*)out + (size_t)n * 32 + m * 2) = o;  // hb
        } else {
            f32x4 o = (f32x4){v0, v1, v2, v3};
            __builtin_nontemporal_store(o, (f32x4*)((float*)out + (size_t)n * 64 + m * 4));
        }
    }
}

extern "C" void kernel_launch(void* const* d_in, const int* in_sizes, int n_in,
                              void* d_out, int out_size, void* d_ws, size_t ws_size,
                              hipStream_t stream) {
    const float* x  = (const float*)d_in[0];
    const int*   ei = (const int*)d_in[1];
    const float* bq1 = (const float*)d_in[3];
    const float* bk1 = (const float*)d_in[5];
    const float* bv1 = (const float*)d_in[7];
    const float* bs1 = (const float*)d_in[9];
    const float* bq2 = (const float*)d_in[11];
    const float* bk2 = (const float*)d_in[13];
    const float* bv2 = (const float*)d_in[15];
    const float* bs2 = (const float*)d_in[17];

    WPtrs wp;
    wp.p[0] = (const float*)d_in[2];
    wp.p[1] = (const float*)d_in[4];
    wp.p[2] = (const float*)d_in[6];
    wp.p[3] = (const float*)d_in[8];
    wp.p[4] = (const float*)d_in[10];
    wp.p[5] = (const float*)d_in[12];
    wp.p[6] = (const float*)d_in[14];
    wp.p[7] = (const float*)d_in[16];

    const size_t N = N_NODES;
    bf16* hb  = (bf16*)d_ws;                 // NPAD*64
    bf16* qb  = hb + (size_t)NPAD * 64;      // N*64
    bf16* kvb = qb + N * 64;                 // 2*N*64 interleaved
    bf16* wb  = kvb + 2 * N * 64;            // 49152
    bf16* sb  = wb + 49152;                  // N*64 (bf16)
    int* off  = (int*)(sb + N * 64);         // N+1
    int* gcur = off + N_NODES + 1;           // NBK*CURSTRIDE
    unsigned short* csr = (unsigned short*)(gcur + NBK * CURSTRIDE); // E u16
    unsigned int* pairs = (unsigned int*)(csr + N_EDGES);            // NBK*CAP

    const int aggGrid = (N_NODES * 64 + 255) / 256;

    // ---------------- prep (w-conv + gcur zero; tiny) ----------------
    prep<<<64, 256, 0, stream>>>(wp, wb, gcur);

    // ---------------- Layer 1 (scatter-first + gemm w/ LDS-staged x) -------
    gemm1_scatter<<<GEMM_BLKS + SCAT_BLKS, 256, 0, stream>>>(
        x, wb, bq1, bk1, bv1, bs1, qb, kvb, sb, ei, gcur, pairs);
    passB<<<NBK, 512, 0, stream>>>(gcur, pairs, csr, off);
    agg_csr<4, true, bf16><<<aggGrid, 256, 0, stream>>>(off, csr, qb,
                                                        (const unsigned int*)kvb, sb, hb);

    // ---------------- Layer 2 ----------------
    gemm2<<<GEMM_BLKS, 256, 0, stream>>>(hb, wb + 32768, bq2, bk2, bv2, bs2,
                                         qb, kvb, sb);
    agg_csr<1, false, float><<<aggGrid, 256, 0, stream>>>(off, csr, qb,
                                                          (const unsigned int*)kvb, sb,
                                                          (float*)d_out);
}